// Round 1
// baseline (1912.892 us; speedup 1.0000x reference)
//
#include <hip/hip_runtime.h>
#include <stdint.h>

#define NPTS 4096
#define KREG 1024
#define NS   64
#define NB   16
#define PTOT (NB*KREG*NS)        // 1048576 positions
#define NWAVE (PTOT/64)          // 16384
#define GATH_BLOCKS 256

// ---------------------------------------------------------------------------
// FPS: one block per batch, 1024 threads, 4 points/thread. Exact f32 (no FMA)
// to match numpy reference; argmax first-index tie-break via packed u64 key.
// Writes centroids (B,3,K) directly into d_out.
// ---------------------------------------------------------------------------
__global__ __launch_bounds__(1024) void fps_kernel(
    const float* __restrict__ pc, float* __restrict__ outC)
{
    __shared__ float xs[NPTS];
    __shared__ float ys[NPTS];
    __shared__ float zs[NPTS];
    __shared__ unsigned long long wkey[16];
    __shared__ int curF;

    const int b = blockIdx.x;
    const int t = threadIdx.x;
    const float* px = pc + (size_t)b * 3 * NPTS;

    for (int i = t; i < NPTS; i += 1024) {
        xs[i] = px[i];
        ys[i] = px[NPTS + i];
        zs[i] = px[2 * NPTS + i];
    }
    if (t == 0) curF = 0;
    __syncthreads();

    float md[4] = {1e10f, 1e10f, 1e10f, 1e10f};

    for (int it = 0; it < KREG; ++it) {
        int f = curF;
        if (t == 0) {
            outC[(size_t)b * 3 * KREG + it]            = xs[f];
            outC[(size_t)b * 3 * KREG + KREG + it]     = ys[f];
            outC[(size_t)b * 3 * KREG + 2 * KREG + it] = zs[f];
        }
        float cx = xs[f], cy = ys[f], cz = zs[f];

        unsigned long long best = 0ull;
        #pragma unroll
        for (int j = 0; j < 4; ++j) {
            int p = j * 1024 + t;
            float dx = __fsub_rn(xs[p], cx);
            float dy = __fsub_rn(ys[p], cy);
            float dz = __fsub_rn(zs[p], cz);
            float d = __fadd_rn(__fadd_rn(__fmul_rn(dx, dx), __fmul_rn(dy, dy)),
                                __fmul_rn(dz, dz));
            float m = fminf(md[j], d);
            md[j] = m;
            unsigned long long key =
                ((unsigned long long)__float_as_uint(m) << 32) |
                (unsigned long long)(0xFFFFFFFFu - (unsigned)p);
            if (key > best) best = key;
        }
        // wave-level max
        #pragma unroll
        for (int s = 32; s > 0; s >>= 1) {
            unsigned long long o = __shfl_xor(best, s, 64);
            if (o > best) best = o;
        }
        if ((t & 63) == 0) wkey[t >> 6] = best;
        __syncthreads();
        if (t < 64) {
            unsigned long long k2 = (t < 16) ? wkey[t] : 0ull;
            #pragma unroll
            for (int s = 8; s > 0; s >>= 1) {
                unsigned long long o = __shfl_xor(k2, s, 64);
                if (o > k2) k2 = o;
            }
            if (t == 0) curF = (int)(0xFFFFFFFFu - (unsigned)(k2 & 0xFFFFFFFFull));
        }
        __syncthreads();
    }
}

// ---------------------------------------------------------------------------
// Ball query: one wave per centroid. Exact f32 (c2+x2)-2*dot formula.
// Keeps first NS in-radius indices in ascending order; pads with first index.
// ---------------------------------------------------------------------------
__global__ __launch_bounds__(256) void ballquery_kernel(
    const float* __restrict__ pc, const float* __restrict__ outC,
    int* __restrict__ gidx)
{
    int gw = blockIdx.x * 4 + (threadIdx.x >> 6);
    int lane = threadIdx.x & 63;
    int b = gw >> 10;
    int k = gw & (KREG - 1);
    const float* px = pc + (size_t)b * 3 * NPTS;

    float cx = outC[(size_t)b * 3 * KREG + k];
    float cy = outC[(size_t)b * 3 * KREG + KREG + k];
    float cz = outC[(size_t)b * 3 * KREG + 2 * KREG + k];
    float c2 = __fadd_rn(__fadd_rn(__fmul_rn(cx, cx), __fmul_rn(cy, cy)),
                         __fmul_rn(cz, cz));
    const float r2 = 0.16f;
    int base = gw * NS;
    int cnt = 0;
    int firstidx = -1;

    for (int nb = 0; nb < NPTS / 64; ++nb) {
        int n = nb * 64 + lane;
        float x = px[n], y = px[NPTS + n], z = px[2 * NPTS + n];
        float x2 = __fadd_rn(__fadd_rn(__fmul_rn(x, x), __fmul_rn(y, y)),
                             __fmul_rn(z, z));
        float dt = __fadd_rn(__fadd_rn(__fmul_rn(cx, x), __fmul_rn(cy, y)),
                             __fmul_rn(cz, z));
        float sqd = __fsub_rn(__fadd_rn(c2, x2), __fmul_rn(2.0f, dt));
        bool pred = (sqd <= r2);
        unsigned long long mask = __ballot(pred);
        if (firstidx < 0 && mask) firstidx = nb * 64 + __ffsll((long long)mask) - 1;
        int pos = cnt + __popcll(mask & ((1ull << lane) - 1ull));
        if (pred && pos < NS) gidx[base + pos] = n;
        cnt += __popcll(mask);
        if (cnt >= NS) break;
    }
    if (lane >= cnt) gidx[base + lane] = firstidx;
}

// ---------------------------------------------------------------------------
// Gather grouped coords (planar (3,P)) + 3x3 second-moment partials for BN1.
// ---------------------------------------------------------------------------
__global__ __launch_bounds__(256) void gather_kernel(
    const float* __restrict__ pc, const float* __restrict__ outC,
    const int* __restrict__ gidx, float* __restrict__ X0,
    float* __restrict__ mpart)
{
    float a[9] = {0, 0, 0, 0, 0, 0, 0, 0, 0};
    for (int p = blockIdx.x * 256 + threadIdx.x; p < PTOT; p += GATH_BLOCKS * 256) {
        int bk = p >> 6;
        int b = bk >> 10;
        int k = bk & (KREG - 1);
        int idx = gidx[p];
        const float* px = pc + (size_t)b * 3 * NPTS;
        float x = px[idx]            - outC[(size_t)b * 3 * KREG + k];
        float y = px[NPTS + idx]     - outC[(size_t)b * 3 * KREG + KREG + k];
        float z = px[2 * NPTS + idx] - outC[(size_t)b * 3 * KREG + 2 * KREG + k];
        X0[p] = x; X0[PTOT + p] = y; X0[2 * PTOT + p] = z;
        a[0] += x;     a[1] += y;     a[2] += z;
        a[3] += x * x; a[4] += y * y; a[5] += z * z;
        a[6] += x * y; a[7] += x * z; a[8] += y * z;
    }
    __shared__ float red[4][9];
    int wv = threadIdx.x >> 6;
    #pragma unroll
    for (int q = 0; q < 9; ++q) {
        float v = a[q];
        #pragma unroll
        for (int s = 32; s > 0; s >>= 1) v += __shfl_xor(v, s, 64);
        if ((threadIdx.x & 63) == 0) red[wv][q] = v;
    }
    __syncthreads();
    if (threadIdx.x < 9) {
        mpart[blockIdx.x * 9 + threadIdx.x] =
            red[0][threadIdx.x] + red[1][threadIdx.x] +
            red[2][threadIdx.x] + red[3][threadIdx.x];
    }
}

// ---------------------------------------------------------------------------
// BN1 params analytically from moments: y1 = W1 x + b1 is linear in x.
// ---------------------------------------------------------------------------
__global__ void bn1_finalize(
    const float* __restrict__ mpart, const float* __restrict__ w1,
    const float* __restrict__ b1, const float* __restrict__ g1,
    const float* __restrict__ be1, float* __restrict__ sc1,
    float* __restrict__ sh1)
{
    __shared__ double M[9];
    int t = threadIdx.x;
    if (t < 9) {
        double s = 0;
        for (int i = 0; i < GATH_BLOCKS; ++i) s += (double)mpart[i * 9 + t];
        M[t] = s / (double)PTOT;
    }
    __syncthreads();
    if (t < 64) {
        double mux = M[0], muy = M[1], muz = M[2];
        double xx = M[3], yy = M[4], zz = M[5], xy = M[6], xz = M[7], yz = M[8];
        double wx = w1[t * 3], wy = w1[t * 3 + 1], wz = w1[t * 3 + 2], bb = b1[t];
        double wmu = wx * mux + wy * muy + wz * muz;
        double mean = wmu + bb;
        double ey2 = wx * wx * xx + wy * wy * yy + wz * wz * zz
                   + 2.0 * (wx * wy * xy + wx * wz * xz + wy * wz * yz)
                   + 2.0 * bb * wmu + bb * bb;
        double var = ey2 - mean * mean;
        double scale = (double)g1[t] / sqrt(var + 1e-5);
        sc1[t] = (float)scale;
        sh1[t] = (float)((double)be1[t] - mean * scale);
    }
}

// ---------------------------------------------------------------------------
// Transpose small weight matrices so conv loops read contiguous (-> s_load).
// ---------------------------------------------------------------------------
__global__ __launch_bounds__(256) void prep_kernel(
    const float* __restrict__ w2, const float* __restrict__ w3,
    float* __restrict__ w2t, float* __restrict__ w3t)
{
    int t = blockIdx.x * 256 + threadIdx.x;
    if (t < 4096) w2t[(t & 63) * 64 + (t >> 6)] = w2[t];
    if (t < 8192) w3t[(t & 63) * 128 + (t >> 6)] = w3[t];
}

// ---------------------------------------------------------------------------
// Pass A: conv1+BN1+ReLU -> conv2, accumulate per-channel sum/sumsq of y2.
// 128 threads/block, 1 position/thread. Activations in LDS columns.
// ---------------------------------------------------------------------------
__global__ __launch_bounds__(128) void conv12_stats_kernel(
    const float* __restrict__ X0,
    const float* __restrict__ w1, const float* __restrict__ b1,
    const float* __restrict__ sc1, const float* __restrict__ sh1,
    const float* __restrict__ w2t, const float* __restrict__ b2,
    float* __restrict__ sum2, float* __restrict__ sq2)
{
    __shared__ float xbuf[64 * 128];
    __shared__ float trans[2][8][65];
    const int t = threadIdx.x;
    const int p = blockIdx.x * 128 + t;

    float x = X0[p], y = X0[PTOT + p], z = X0[2 * PTOT + p];
    #pragma unroll
    for (int o = 0; o < 64; ++o) {
        float v = b1[o];
        v = fmaf(w1[o * 3 + 2], z, v);
        v = fmaf(w1[o * 3 + 1], y, v);
        v = fmaf(w1[o * 3 + 0], x, v);
        v = fmaf(v, sc1[o], sh1[o]);
        xbuf[o * 128 + t] = fmaxf(v, 0.0f);
    }
    float acc[64];
    #pragma unroll
    for (int o = 0; o < 64; ++o) acc[o] = b2[o];
    for (int c = 0; c < 64; ++c) {
        float xv = xbuf[c * 128 + t];
        #pragma unroll
        for (int o = 0; o < 64; ++o) acc[o] = fmaf(w2t[c * 64 + o], xv, acc[o]);
    }
    const int wv = t >> 6, lane = t & 63;
    const int gw = blockIdx.x * 2 + wv;
    #pragma unroll
    for (int ch = 0; ch < 8; ++ch) {
        __syncthreads();
        #pragma unroll
        for (int o = 0; o < 8; ++o) trans[wv][o][lane] = acc[ch * 8 + o];
        __syncthreads();
        int row = lane >> 3, seg = lane & 7;
        float s = 0.f, q = 0.f;
        #pragma unroll
        for (int j = 0; j < 8; ++j) {
            float v = trans[wv][row][seg * 8 + j];
            s += v; q = fmaf(v, v, q);
        }
        s += __shfl_xor(s, 1, 64); q += __shfl_xor(q, 1, 64);
        s += __shfl_xor(s, 2, 64); q += __shfl_xor(q, 2, 64);
        s += __shfl_xor(s, 4, 64); q += __shfl_xor(q, 4, 64);
        if (seg == 0) {
            int o = ch * 8 + row;
            sum2[(size_t)o * NWAVE + gw] = s;
            sq2[(size_t)o * NWAVE + gw] = q;
        }
    }
}

// ---------------------------------------------------------------------------
// Generic BN finalize: per-channel block sums wave partials (f64), emits
// scale/shift.
// ---------------------------------------------------------------------------
__global__ __launch_bounds__(256) void bn_finalize_kernel(
    const float* __restrict__ sumb, const float* __restrict__ sqb,
    const float* __restrict__ g, const float* __restrict__ be,
    float* __restrict__ sc, float* __restrict__ sh)
{
    int o = blockIdx.x, t = threadIdx.x;
    double s = 0, q = 0;
    for (int i = t; i < NWAVE; i += 256) {
        s += (double)sumb[(size_t)o * NWAVE + i];
        q += (double)sqb[(size_t)o * NWAVE + i];
    }
    #pragma unroll
    for (int m = 32; m > 0; m >>= 1) {
        s += __shfl_xor(s, m, 64);
        q += __shfl_xor(q, m, 64);
    }
    __shared__ double rs[4], rq[4];
    if ((t & 63) == 0) { rs[t >> 6] = s; rq[t >> 6] = q; }
    __syncthreads();
    if (t == 0) {
        s = rs[0] + rs[1] + rs[2] + rs[3];
        q = rq[0] + rq[1] + rq[2] + rq[3];
        double mean = s / (double)PTOT;
        double var = q / (double)PTOT - mean * mean;
        double scale = (double)g[o] / sqrt(var + 1e-5);
        sc[o] = (float)scale;
        sh[o] = (float)((double)be[o] - mean * scale);
    }
}

// ---------------------------------------------------------------------------
// Pass B: recompute conv1->conv2 (BN params now known), conv3; emit per-(bk,o)
// max/min of y3 plus per-channel sum/sumsq partials. y3 never stored.
// ---------------------------------------------------------------------------
__global__ __launch_bounds__(128) void conv123_kernel(
    const float* __restrict__ X0,
    const float* __restrict__ w1, const float* __restrict__ b1,
    const float* __restrict__ sc1, const float* __restrict__ sh1,
    const float* __restrict__ w2t, const float* __restrict__ b2,
    const float* __restrict__ sc2, const float* __restrict__ sh2,
    const float* __restrict__ w3t, const float* __restrict__ b3,
    float* __restrict__ y3max, float* __restrict__ y3min,
    float* __restrict__ sum3, float* __restrict__ sq3)
{
    __shared__ float xbuf[64 * 128];
    __shared__ float trans[2][8][65];
    const int t = threadIdx.x;
    const int p = blockIdx.x * 128 + t;

    float x = X0[p], y = X0[PTOT + p], z = X0[2 * PTOT + p];
    #pragma unroll
    for (int o = 0; o < 64; ++o) {
        float v = b1[o];
        v = fmaf(w1[o * 3 + 2], z, v);
        v = fmaf(w1[o * 3 + 1], y, v);
        v = fmaf(w1[o * 3 + 0], x, v);
        v = fmaf(v, sc1[o], sh1[o]);
        xbuf[o * 128 + t] = fmaxf(v, 0.0f);
    }
    float acc2[64];
    #pragma unroll
    for (int o = 0; o < 64; ++o) acc2[o] = b2[o];
    for (int c = 0; c < 64; ++c) {
        float xv = xbuf[c * 128 + t];
        #pragma unroll
        for (int o = 0; o < 64; ++o) acc2[o] = fmaf(w2t[c * 64 + o], xv, acc2[o]);
    }
    #pragma unroll
    for (int o = 0; o < 64; ++o) {
        xbuf[o * 128 + t] = fmaxf(fmaf(acc2[o], sc2[o], sh2[o]), 0.0f);
    }
    float acc3[128];
    #pragma unroll
    for (int o = 0; o < 128; ++o) acc3[o] = b3[o];
    for (int c = 0; c < 64; ++c) {
        float xv = xbuf[c * 128 + t];
        #pragma unroll
        for (int o = 0; o < 128; ++o) acc3[o] = fmaf(w3t[c * 128 + o], xv, acc3[o]);
    }
    const int wv = t >> 6, lane = t & 63;
    const int gw = blockIdx.x * 2 + wv;   // == bk (group) index
    #pragma unroll
    for (int ch = 0; ch < 16; ++ch) {
        __syncthreads();
        #pragma unroll
        for (int o = 0; o < 8; ++o) trans[wv][o][lane] = acc3[ch * 8 + o];
        __syncthreads();
        int row = lane >> 3, seg = lane & 7;
        float s = 0.f, q = 0.f, mx = -1e30f, mn = 1e30f;
        #pragma unroll
        for (int j = 0; j < 8; ++j) {
            float v = trans[wv][row][seg * 8 + j];
            s += v; q = fmaf(v, v, q);
            mx = fmaxf(mx, v); mn = fminf(mn, v);
        }
        s += __shfl_xor(s, 1, 64); q += __shfl_xor(q, 1, 64);
        mx = fmaxf(mx, __shfl_xor(mx, 1, 64)); mn = fminf(mn, __shfl_xor(mn, 1, 64));
        s += __shfl_xor(s, 2, 64); q += __shfl_xor(q, 2, 64);
        mx = fmaxf(mx, __shfl_xor(mx, 2, 64)); mn = fminf(mn, __shfl_xor(mn, 2, 64));
        s += __shfl_xor(s, 4, 64); q += __shfl_xor(q, 4, 64);
        mx = fmaxf(mx, __shfl_xor(mx, 4, 64)); mn = fminf(mn, __shfl_xor(mn, 4, 64));
        if (seg == 0) {
            int o = ch * 8 + row;
            y3max[(size_t)gw * 128 + o] = mx;
            y3min[(size_t)gw * 128 + o] = mn;
            sum3[(size_t)o * NWAVE + gw] = s;
            sq3[(size_t)o * NWAVE + gw] = q;
        }
    }
}

// ---------------------------------------------------------------------------
// Final: feats[b,o,k] = relu(scale3*extreme + shift3), transposed via LDS.
// max over samples commutes with the monotone BN+ReLU (min if scale<0).
// ---------------------------------------------------------------------------
__global__ __launch_bounds__(256) void feats_kernel(
    const float* __restrict__ y3max, const float* __restrict__ y3min,
    const float* __restrict__ sc3, const float* __restrict__ sh3,
    float* __restrict__ feats)
{
    __shared__ float tile[64][129];
    int blk = blockIdx.x;          // b*16 + kt
    int b = blk >> 4, kt = blk & 15;
    int t = threadIdx.x;
    size_t bk0 = (size_t)(b * KREG + kt * 64);
    #pragma unroll
    for (int i = 0; i < 32; ++i) {
        int idx = i * 256 + t;
        int o = idx & 127, kk = idx >> 7;
        float a = sc3[o];
        float v = (a >= 0.f) ? y3max[(bk0 + kk) * 128 + o]
                             : y3min[(bk0 + kk) * 128 + o];
        tile[kk][o] = fmaxf(fmaf(v, a, sh3[o]), 0.0f);
    }
    __syncthreads();
    #pragma unroll
    for (int i = 0; i < 32; ++i) {
        int idx = i * 256 + t;
        int kk = idx & 63, o = idx >> 6;
        feats[(size_t)b * 128 * KREG + (size_t)o * KREG + kt * 64 + kk] = tile[kk][o];
    }
}

// ---------------------------------------------------------------------------
extern "C" void kernel_launch(void* const* d_in, const int* in_sizes, int n_in,
                              void* d_out, int out_size, void* d_ws, size_t ws_size,
                              hipStream_t stream)
{
    const float* pc  = (const float*)d_in[0];
    const float* w1  = (const float*)d_in[1];
    const float* b1  = (const float*)d_in[2];
    const float* g1  = (const float*)d_in[3];
    const float* be1 = (const float*)d_in[4];
    const float* w2  = (const float*)d_in[5];
    const float* b2  = (const float*)d_in[6];
    const float* g2  = (const float*)d_in[7];
    const float* be2 = (const float*)d_in[8];
    const float* w3  = (const float*)d_in[9];
    const float* b3  = (const float*)d_in[10];
    const float* g3  = (const float*)d_in[11];
    const float* be3 = (const float*)d_in[12];

    float* outC  = (float*)d_out;                      // (16,3,1024)
    float* feats = (float*)d_out + NB * 3 * KREG;      // (16,128,1024)

    const size_t MB = 1024 * 1024;
    char* ws = (char*)d_ws;
    int*   gidx  = (int*)ws;                           // 4 MB
    float* X0    = (float*)(ws + 4 * MB);              // 12 MB (3 x P)
    float* mpart = (float*)(ws + 16 * MB);             // 9216 B
    float* sc1   = (float*)(ws + 16 * MB + 16 * 1024);
    float* sh1   = (float*)(ws + 16 * MB + 17 * 1024);
    float* sc2   = (float*)(ws + 16 * MB + 18 * 1024);
    float* sh2   = (float*)(ws + 16 * MB + 19 * 1024);
    float* sc3   = (float*)(ws + 16 * MB + 20 * 1024);
    float* sh3   = (float*)(ws + 16 * MB + 21 * 1024);
    float* w2t   = (float*)(ws + 16 * MB + 32 * 1024); // 16 KB
    float* w3t   = (float*)(ws + 16 * MB + 64 * 1024); // 32 KB
    float* sum2  = (float*)(ws + 17 * MB);             // 4 MB
    float* sq2   = (float*)(ws + 21 * MB);             // 4 MB
    float* sum3  = (float*)(ws + 25 * MB);             // 8 MB
    float* sq3   = (float*)(ws + 33 * MB);             // 8 MB
    float* y3max = (float*)(ws + 41 * MB);             // 8 MB
    float* y3min = (float*)(ws + 49 * MB);             // 8 MB

    fps_kernel<<<NB, 1024, 0, stream>>>(pc, outC);
    ballquery_kernel<<<(NB * KREG) / 4, 256, 0, stream>>>(pc, outC, gidx);
    gather_kernel<<<GATH_BLOCKS, 256, 0, stream>>>(pc, outC, gidx, X0, mpart);
    bn1_finalize<<<1, 64, 0, stream>>>(mpart, w1, b1, g1, be1, sc1, sh1);
    prep_kernel<<<32, 256, 0, stream>>>(w2, w3, w2t, w3t);
    conv12_stats_kernel<<<PTOT / 128, 128, 0, stream>>>(
        X0, w1, b1, sc1, sh1, w2t, b2, sum2, sq2);
    bn_finalize_kernel<<<64, 256, 0, stream>>>(sum2, sq2, g2, be2, sc2, sh2);
    conv123_kernel<<<PTOT / 128, 128, 0, stream>>>(
        X0, w1, b1, sc1, sh1, w2t, b2, sc2, sh2, w3t, b3,
        y3max, y3min, sum3, sq3);
    bn_finalize_kernel<<<128, 256, 0, stream>>>(sum3, sq3, g3, be3, sc3, sh3);
    feats_kernel<<<NB * (KREG / 64), 256, 0, stream>>>(y3max, y3min, sc3, sh3, feats);
}

// Round 2
// 1908.232 us; speedup vs baseline: 1.0024x; 1.0024x over previous
//
#include <hip/hip_runtime.h>
#include <stdint.h>

#define NPTS 4096
#define KREG 1024
#define NS   64
#define NB   16
#define PTOT (NB*KREG*NS)        // 1048576 positions
#define NWAVE (PTOT/64)          // 16384
#define GATH_BLOCKS 256

// ---------------------------------------------------------------------------
// FPS: one block per batch, 1024 threads, 4 points/thread. Exact f32 (no FMA)
// to match numpy reference; argmax first-index tie-break via packed u64 key.
// Writes centroids (B,3,K) directly into d_out.
// ---------------------------------------------------------------------------
__global__ __launch_bounds__(1024) void fps_kernel(
    const float* __restrict__ pc, float* __restrict__ outC)
{
    __shared__ float xs[NPTS];
    __shared__ float ys[NPTS];
    __shared__ float zs[NPTS];
    __shared__ unsigned long long wkey[16];
    __shared__ int curF;

    const int b = blockIdx.x;
    const int t = threadIdx.x;
    const float* px = pc + (size_t)b * 3 * NPTS;

    for (int i = t; i < NPTS; i += 1024) {
        xs[i] = px[i];
        ys[i] = px[NPTS + i];
        zs[i] = px[2 * NPTS + i];
    }
    if (t == 0) curF = 0;
    __syncthreads();

    float md[4] = {1e10f, 1e10f, 1e10f, 1e10f};

    for (int it = 0; it < KREG; ++it) {
        int f = curF;
        if (t == 0) {
            outC[(size_t)b * 3 * KREG + it]            = xs[f];
            outC[(size_t)b * 3 * KREG + KREG + it]     = ys[f];
            outC[(size_t)b * 3 * KREG + 2 * KREG + it] = zs[f];
        }
        float cx = xs[f], cy = ys[f], cz = zs[f];

        unsigned long long best = 0ull;
        #pragma unroll
        for (int j = 0; j < 4; ++j) {
            int p = j * 1024 + t;
            float dx = __fsub_rn(xs[p], cx);
            float dy = __fsub_rn(ys[p], cy);
            float dz = __fsub_rn(zs[p], cz);
            float d = __fadd_rn(__fadd_rn(__fmul_rn(dx, dx), __fmul_rn(dy, dy)),
                                __fmul_rn(dz, dz));
            float m = fminf(md[j], d);
            md[j] = m;
            unsigned long long key =
                ((unsigned long long)__float_as_uint(m) << 32) |
                (unsigned long long)(0xFFFFFFFFu - (unsigned)p);
            if (key > best) best = key;
        }
        // wave-level max
        #pragma unroll
        for (int s = 32; s > 0; s >>= 1) {
            unsigned long long o = __shfl_xor(best, s, 64);
            if (o > best) best = o;
        }
        if ((t & 63) == 0) wkey[t >> 6] = best;
        __syncthreads();
        if (t < 64) {
            unsigned long long k2 = (t < 16) ? wkey[t] : 0ull;
            #pragma unroll
            for (int s = 8; s > 0; s >>= 1) {
                unsigned long long o = __shfl_xor(k2, s, 64);
                if (o > k2) k2 = o;
            }
            if (t == 0) curF = (int)(0xFFFFFFFFu - (unsigned)(k2 & 0xFFFFFFFFull));
        }
        __syncthreads();
    }
}

// ---------------------------------------------------------------------------
// Ball query: one wave per centroid. Exact f32 (c2+x2)-2*dot formula.
// Keeps first NS in-radius indices in ascending order; pads with first index.
// ---------------------------------------------------------------------------
__global__ __launch_bounds__(256) void ballquery_kernel(
    const float* __restrict__ pc, const float* __restrict__ outC,
    int* __restrict__ gidx)
{
    int gw = blockIdx.x * 4 + (threadIdx.x >> 6);
    int lane = threadIdx.x & 63;
    int b = gw >> 10;
    int k = gw & (KREG - 1);
    const float* px = pc + (size_t)b * 3 * NPTS;

    float cx = outC[(size_t)b * 3 * KREG + k];
    float cy = outC[(size_t)b * 3 * KREG + KREG + k];
    float cz = outC[(size_t)b * 3 * KREG + 2 * KREG + k];
    float c2 = __fadd_rn(__fadd_rn(__fmul_rn(cx, cx), __fmul_rn(cy, cy)),
                         __fmul_rn(cz, cz));
    const float r2 = 0.16f;
    int base = gw * NS;
    int cnt = 0;
    int firstidx = -1;

    for (int nb = 0; nb < NPTS / 64; ++nb) {
        int n = nb * 64 + lane;
        float x = px[n], y = px[NPTS + n], z = px[2 * NPTS + n];
        float x2 = __fadd_rn(__fadd_rn(__fmul_rn(x, x), __fmul_rn(y, y)),
                             __fmul_rn(z, z));
        float dt = __fadd_rn(__fadd_rn(__fmul_rn(cx, x), __fmul_rn(cy, y)),
                             __fmul_rn(cz, z));
        float sqd = __fsub_rn(__fadd_rn(c2, x2), __fmul_rn(2.0f, dt));
        bool pred = (sqd <= r2);
        unsigned long long mask = __ballot(pred);
        if (firstidx < 0 && mask) firstidx = nb * 64 + __ffsll((long long)mask) - 1;
        int pos = cnt + __popcll(mask & ((1ull << lane) - 1ull));
        if (pred && pos < NS) gidx[base + pos] = n;
        cnt += __popcll(mask);
        if (cnt >= NS) break;
    }
    if (lane >= cnt) gidx[base + lane] = firstidx;
}

// ---------------------------------------------------------------------------
// Gather grouped coords (planar (3,P)) + 3x3 second-moment partials for BN1.
// ---------------------------------------------------------------------------
__global__ __launch_bounds__(256) void gather_kernel(
    const float* __restrict__ pc, const float* __restrict__ outC,
    const int* __restrict__ gidx, float* __restrict__ X0,
    float* __restrict__ mpart)
{
    float a[9] = {0, 0, 0, 0, 0, 0, 0, 0, 0};
    for (int p = blockIdx.x * 256 + threadIdx.x; p < PTOT; p += GATH_BLOCKS * 256) {
        int bk = p >> 6;
        int b = bk >> 10;
        int k = bk & (KREG - 1);
        int idx = gidx[p];
        const float* px = pc + (size_t)b * 3 * NPTS;
        float x = px[idx]            - outC[(size_t)b * 3 * KREG + k];
        float y = px[NPTS + idx]     - outC[(size_t)b * 3 * KREG + KREG + k];
        float z = px[2 * NPTS + idx] - outC[(size_t)b * 3 * KREG + 2 * KREG + k];
        X0[p] = x; X0[PTOT + p] = y; X0[2 * PTOT + p] = z;
        a[0] += x;     a[1] += y;     a[2] += z;
        a[3] += x * x; a[4] += y * y; a[5] += z * z;
        a[6] += x * y; a[7] += x * z; a[8] += y * z;
    }
    __shared__ float red[4][9];
    int wv = threadIdx.x >> 6;
    #pragma unroll
    for (int q = 0; q < 9; ++q) {
        float v = a[q];
        #pragma unroll
        for (int s = 32; s > 0; s >>= 1) v += __shfl_xor(v, s, 64);
        if ((threadIdx.x & 63) == 0) red[wv][q] = v;
    }
    __syncthreads();
    if (threadIdx.x < 9) {
        mpart[blockIdx.x * 9 + threadIdx.x] =
            red[0][threadIdx.x] + red[1][threadIdx.x] +
            red[2][threadIdx.x] + red[3][threadIdx.x];
    }
}

// ---------------------------------------------------------------------------
// BN1 params analytically from moments: y1 = W1 x + b1 is linear in x.
// ---------------------------------------------------------------------------
__global__ void bn1_finalize(
    const float* __restrict__ mpart, const float* __restrict__ w1,
    const float* __restrict__ b1, const float* __restrict__ g1,
    const float* __restrict__ be1, float* __restrict__ sc1,
    float* __restrict__ sh1)
{
    __shared__ double M[9];
    int t = threadIdx.x;
    if (t < 9) {
        double s = 0;
        for (int i = 0; i < GATH_BLOCKS; ++i) s += (double)mpart[i * 9 + t];
        M[t] = s / (double)PTOT;
    }
    __syncthreads();
    if (t < 64) {
        double mux = M[0], muy = M[1], muz = M[2];
        double xx = M[3], yy = M[4], zz = M[5], xy = M[6], xz = M[7], yz = M[8];
        double wx = w1[t * 3], wy = w1[t * 3 + 1], wz = w1[t * 3 + 2], bb = b1[t];
        double wmu = wx * mux + wy * muy + wz * muz;
        double mean = wmu + bb;
        double ey2 = wx * wx * xx + wy * wy * yy + wz * wz * zz
                   + 2.0 * (wx * wy * xy + wx * wz * xz + wy * wz * yz)
                   + 2.0 * bb * wmu + bb * bb;
        double var = ey2 - mean * mean;
        double scale = (double)g1[t] / sqrt(var + 1e-5);
        sc1[t] = (float)scale;
        sh1[t] = (float)((double)be1[t] - mean * scale);
    }
}

// ---------------------------------------------------------------------------
// Transpose small weight matrices so conv loops read contiguous (-> s_load).
// ---------------------------------------------------------------------------
__global__ __launch_bounds__(256) void prep_kernel(
    const float* __restrict__ w2, const float* __restrict__ w3,
    float* __restrict__ w2t, float* __restrict__ w3t)
{
    int t = blockIdx.x * 256 + threadIdx.x;
    if (t < 4096) w2t[(t & 63) * 64 + (t >> 6)] = w2[t];
    if (t < 8192) w3t[(t & 63) * 128 + (t >> 6)] = w3[t];
}

// ---------------------------------------------------------------------------
// Pass A: conv1+BN1+ReLU -> conv2, accumulate per-channel sum/sumsq of y2.
// 128 threads/block, 1 position/thread. Activations in LDS columns.
// ---------------------------------------------------------------------------
__global__ __launch_bounds__(128) void conv12_stats_kernel(
    const float* __restrict__ X0,
    const float* __restrict__ w1, const float* __restrict__ b1,
    const float* __restrict__ sc1, const float* __restrict__ sh1,
    const float* __restrict__ w2t, const float* __restrict__ b2,
    float* __restrict__ sum2, float* __restrict__ sq2)
{
    __shared__ float xbuf[64 * 128];
    __shared__ float trans[2][8][65];
    const int t = threadIdx.x;
    const int p = blockIdx.x * 128 + t;

    float x = X0[p], y = X0[PTOT + p], z = X0[2 * PTOT + p];
    #pragma unroll
    for (int o = 0; o < 64; ++o) {
        float v = b1[o];
        v = fmaf(w1[o * 3 + 2], z, v);
        v = fmaf(w1[o * 3 + 1], y, v);
        v = fmaf(w1[o * 3 + 0], x, v);
        v = fmaf(v, sc1[o], sh1[o]);
        xbuf[o * 128 + t] = fmaxf(v, 0.0f);
    }
    float acc[64];
    #pragma unroll
    for (int o = 0; o < 64; ++o) acc[o] = b2[o];
    for (int c = 0; c < 64; ++c) {
        float xv = xbuf[c * 128 + t];
        #pragma unroll
        for (int o = 0; o < 64; ++o) acc[o] = fmaf(w2t[c * 64 + o], xv, acc[o]);
    }
    const int wv = t >> 6, lane = t & 63;
    const int gw = blockIdx.x * 2 + wv;
    #pragma unroll
    for (int ch = 0; ch < 8; ++ch) {
        __syncthreads();
        #pragma unroll
        for (int o = 0; o < 8; ++o) trans[wv][o][lane] = acc[ch * 8 + o];
        __syncthreads();
        int row = lane >> 3, seg = lane & 7;
        float s = 0.f, q = 0.f;
        #pragma unroll
        for (int j = 0; j < 8; ++j) {
            float v = trans[wv][row][seg * 8 + j];
            s += v; q = fmaf(v, v, q);
        }
        s += __shfl_xor(s, 1, 64); q += __shfl_xor(q, 1, 64);
        s += __shfl_xor(s, 2, 64); q += __shfl_xor(q, 2, 64);
        s += __shfl_xor(s, 4, 64); q += __shfl_xor(q, 4, 64);
        if (seg == 0) {
            int o = ch * 8 + row;
            sum2[(size_t)o * NWAVE + gw] = s;
            sq2[(size_t)o * NWAVE + gw] = q;
        }
    }
}

// ---------------------------------------------------------------------------
// Generic BN finalize: per-channel block sums wave partials (f64), emits
// scale/shift.
// ---------------------------------------------------------------------------
__global__ __launch_bounds__(256) void bn_finalize_kernel(
    const float* __restrict__ sumb, const float* __restrict__ sqb,
    const float* __restrict__ g, const float* __restrict__ be,
    float* __restrict__ sc, float* __restrict__ sh)
{
    int o = blockIdx.x, t = threadIdx.x;
    double s = 0, q = 0;
    for (int i = t; i < NWAVE; i += 256) {
        s += (double)sumb[(size_t)o * NWAVE + i];
        q += (double)sqb[(size_t)o * NWAVE + i];
    }
    #pragma unroll
    for (int m = 32; m > 0; m >>= 1) {
        s += __shfl_xor(s, m, 64);
        q += __shfl_xor(q, m, 64);
    }
    __shared__ double rs[4], rq[4];
    if ((t & 63) == 0) { rs[t >> 6] = s; rq[t >> 6] = q; }
    __syncthreads();
    if (t == 0) {
        s = rs[0] + rs[1] + rs[2] + rs[3];
        q = rq[0] + rq[1] + rq[2] + rq[3];
        double mean = s / (double)PTOT;
        double var = q / (double)PTOT - mean * mean;
        double scale = (double)g[o] / sqrt(var + 1e-5);
        sc[o] = (float)scale;
        sh[o] = (float)((double)be[o] - mean * scale);
    }
}

// ---------------------------------------------------------------------------
// Pass B: recompute conv1->conv2 (BN params now known), conv3; emit per-(bk,o)
// max/min of y3 plus per-channel sum/sumsq partials. y3 never stored.
// ---------------------------------------------------------------------------
__global__ __launch_bounds__(128) void conv123_kernel(
    const float* __restrict__ X0,
    const float* __restrict__ w1, const float* __restrict__ b1,
    const float* __restrict__ sc1, const float* __restrict__ sh1,
    const float* __restrict__ w2t, const float* __restrict__ b2,
    const float* __restrict__ sc2, const float* __restrict__ sh2,
    const float* __restrict__ w3t, const float* __restrict__ b3,
    float* __restrict__ y3max, float* __restrict__ y3min,
    float* __restrict__ sum3, float* __restrict__ sq3)
{
    __shared__ float xbuf[64 * 128];
    __shared__ float trans[2][8][65];
    const int t = threadIdx.x;
    const int p = blockIdx.x * 128 + t;

    float x = X0[p], y = X0[PTOT + p], z = X0[2 * PTOT + p];
    #pragma unroll
    for (int o = 0; o < 64; ++o) {
        float v = b1[o];
        v = fmaf(w1[o * 3 + 2], z, v);
        v = fmaf(w1[o * 3 + 1], y, v);
        v = fmaf(w1[o * 3 + 0], x, v);
        v = fmaf(v, sc1[o], sh1[o]);
        xbuf[o * 128 + t] = fmaxf(v, 0.0f);
    }
    float acc2[64];
    #pragma unroll
    for (int o = 0; o < 64; ++o) acc2[o] = b2[o];
    for (int c = 0; c < 64; ++c) {
        float xv = xbuf[c * 128 + t];
        #pragma unroll
        for (int o = 0; o < 64; ++o) acc2[o] = fmaf(w2t[c * 64 + o], xv, acc2[o]);
    }
    #pragma unroll
    for (int o = 0; o < 64; ++o) {
        xbuf[o * 128 + t] = fmaxf(fmaf(acc2[o], sc2[o], sh2[o]), 0.0f);
    }
    float acc3[128];
    #pragma unroll
    for (int o = 0; o < 128; ++o) acc3[o] = b3[o];
    for (int c = 0; c < 64; ++c) {
        float xv = xbuf[c * 128 + t];
        #pragma unroll
        for (int o = 0; o < 128; ++o) acc3[o] = fmaf(w3t[c * 128 + o], xv, acc3[o]);
    }
    const int wv = t >> 6, lane = t & 63;
    const int gw = blockIdx.x * 2 + wv;   // == bk (group) index
    #pragma unroll
    for (int ch = 0; ch < 16; ++ch) {
        __syncthreads();
        #pragma unroll
        for (int o = 0; o < 8; ++o) trans[wv][o][lane] = acc3[ch * 8 + o];
        __syncthreads();
        int row = lane >> 3, seg = lane & 7;
        float s = 0.f, q = 0.f, mx = -1e30f, mn = 1e30f;
        #pragma unroll
        for (int j = 0; j < 8; ++j) {
            float v = trans[wv][row][seg * 8 + j];
            s += v; q = fmaf(v, v, q);
            mx = fmaxf(mx, v); mn = fminf(mn, v);
        }
        s += __shfl_xor(s, 1, 64); q += __shfl_xor(q, 1, 64);
        mx = fmaxf(mx, __shfl_xor(mx, 1, 64)); mn = fminf(mn, __shfl_xor(mn, 1, 64));
        s += __shfl_xor(s, 2, 64); q += __shfl_xor(q, 2, 64);
        mx = fmaxf(mx, __shfl_xor(mx, 2, 64)); mn = fminf(mn, __shfl_xor(mn, 2, 64));
        s += __shfl_xor(s, 4, 64); q += __shfl_xor(q, 4, 64);
        mx = fmaxf(mx, __shfl_xor(mx, 4, 64)); mn = fminf(mn, __shfl_xor(mn, 4, 64));
        if (seg == 0) {
            int o = ch * 8 + row;
            y3max[(size_t)gw * 128 + o] = mx;
            y3min[(size_t)gw * 128 + o] = mn;
            sum3[(size_t)o * NWAVE + gw] = s;
            sq3[(size_t)o * NWAVE + gw] = q;
        }
    }
}

// ---------------------------------------------------------------------------
// Final: feats[b,o,k] = relu(scale3*extreme + shift3), transposed via LDS.
// max over samples commutes with the monotone BN+ReLU (min if scale<0).
// ---------------------------------------------------------------------------
__global__ __launch_bounds__(256) void feats_kernel(
    const float* __restrict__ y3max, const float* __restrict__ y3min,
    const float* __restrict__ sc3, const float* __restrict__ sh3,
    float* __restrict__ feats)
{
    __shared__ float tile[64][129];
    int blk = blockIdx.x;          // b*16 + kt
    int b = blk >> 4, kt = blk & 15;
    int t = threadIdx.x;
    size_t bk0 = (size_t)(b * KREG + kt * 64);
    #pragma unroll
    for (int i = 0; i < 32; ++i) {
        int idx = i * 256 + t;
        int o = idx & 127, kk = idx >> 7;
        float a = sc3[o];
        float v = (a >= 0.f) ? y3max[(bk0 + kk) * 128 + o]
                             : y3min[(bk0 + kk) * 128 + o];
        tile[kk][o] = fmaxf(fmaf(v, a, sh3[o]), 0.0f);
    }
    __syncthreads();
    #pragma unroll
    for (int i = 0; i < 32; ++i) {
        int idx = i * 256 + t;
        int kk = idx & 63, o = idx >> 6;
        feats[(size_t)b * 128 * KREG + (size_t)o * KREG + kt * 64 + kk] = tile[kk][o];
    }
}

// ---------------------------------------------------------------------------
extern "C" void kernel_launch(void* const* d_in, const int* in_sizes, int n_in,
                              void* d_out, int out_size, void* d_ws, size_t ws_size,
                              hipStream_t stream)
{
    const float* pc  = (const float*)d_in[0];
    const float* w1  = (const float*)d_in[1];
    const float* b1  = (const float*)d_in[2];
    const float* g1  = (const float*)d_in[3];
    const float* be1 = (const float*)d_in[4];
    const float* w2  = (const float*)d_in[5];
    const float* b2  = (const float*)d_in[6];
    const float* g2  = (const float*)d_in[7];
    const float* be2 = (const float*)d_in[8];
    const float* w3  = (const float*)d_in[9];
    const float* b3  = (const float*)d_in[10];
    const float* g3  = (const float*)d_in[11];
    const float* be3 = (const float*)d_in[12];

    float* outC  = (float*)d_out;                      // (16,3,1024)
    float* feats = (float*)d_out + NB * 3 * KREG;      // (16,128,1024)

    const size_t MB = 1024 * 1024;
    char* ws = (char*)d_ws;
    int*   gidx  = (int*)ws;                           // 4 MB
    float* X0    = (float*)(ws + 4 * MB);              // 12 MB (3 x P)
    float* mpart = (float*)(ws + 16 * MB);             // 9216 B
    float* sc1   = (float*)(ws + 16 * MB + 16 * 1024);
    float* sh1   = (float*)(ws + 16 * MB + 17 * 1024);
    float* sc2   = (float*)(ws + 16 * MB + 18 * 1024);
    float* sh2   = (float*)(ws + 16 * MB + 19 * 1024);
    float* sc3   = (float*)(ws + 16 * MB + 20 * 1024);
    float* sh3   = (float*)(ws + 16 * MB + 21 * 1024);
    float* w2t   = (float*)(ws + 16 * MB + 32 * 1024); // 16 KB
    float* w3t   = (float*)(ws + 16 * MB + 64 * 1024); // 32 KB
    float* sum2  = (float*)(ws + 17 * MB);             // 4 MB
    float* sq2   = (float*)(ws + 21 * MB);             // 4 MB
    float* sum3  = (float*)(ws + 25 * MB);             // 8 MB
    float* sq3   = (float*)(ws + 33 * MB);             // 8 MB
    float* y3max = (float*)(ws + 41 * MB);             // 8 MB
    float* y3min = (float*)(ws + 49 * MB);             // 8 MB

    fps_kernel<<<NB, 1024, 0, stream>>>(pc, outC);
    ballquery_kernel<<<(NB * KREG) / 4, 256, 0, stream>>>(pc, outC, gidx);
    gather_kernel<<<GATH_BLOCKS, 256, 0, stream>>>(pc, outC, gidx, X0, mpart);
    bn1_finalize<<<1, 64, 0, stream>>>(mpart, w1, b1, g1, be1, sc1, sh1);
    prep_kernel<<<32, 256, 0, stream>>>(w2, w3, w2t, w3t);
    conv12_stats_kernel<<<PTOT / 128, 128, 0, stream>>>(
        X0, w1, b1, sc1, sh1, w2t, b2, sum2, sq2);
    bn_finalize_kernel<<<64, 256, 0, stream>>>(sum2, sq2, g2, be2, sc2, sh2);
    conv123_kernel<<<PTOT / 128, 128, 0, stream>>>(
        X0, w1, b1, sc1, sh1, w2t, b2, sc2, sh2, w3t, b3,
        y3max, y3min, sum3, sq3);
    bn_finalize_kernel<<<128, 256, 0, stream>>>(sum3, sq3, g3, be3, sc3, sh3);
    feats_kernel<<<NB * (KREG / 64), 256, 0, stream>>>(y3max, y3min, sc3, sh3, feats);
}

// Round 3
// 1617.367 us; speedup vs baseline: 1.1827x; 1.1798x over previous
//
#include <hip/hip_runtime.h>
#include <stdint.h>

#define NPTS 4096
#define KREG 1024
#define NS   64
#define NB   16
#define PTOT (NB*KREG*NS)        // 1048576 positions
#define NWAVE (PTOT/64)          // 16384
#define GATH_BLOCKS 256

// ---------------------------------------------------------------------------
// FPS: one block per batch, 1024 threads, 4 points/thread held in REGISTERS.
// Exact f32 (no FMA) to match numpy reference; argmax first-index tie-break
// via packed u64 key (m_bits<<32 | ~idx). One barrier per iteration:
// wave reduce -> per-wave LDS atomicMax into rotating 3-deep slot -> barrier
// -> broadcast read. Centroid fetched as a single float4 LDS read.
// Writes centroids (B,3,K) directly into d_out.
// ---------------------------------------------------------------------------
__global__ __launch_bounds__(1024) void fps_kernel(
    const float* __restrict__ pc, float* __restrict__ outC)
{
    __shared__ float4 pcL[NPTS];                 // 64 KB
    __shared__ unsigned long long keySlot[3];

    const int b = blockIdx.x;
    const int t = threadIdx.x;
    const float* px = pc + (size_t)b * 3 * NPTS;

    float lx[4], ly[4], lz[4];
    #pragma unroll
    for (int j = 0; j < 4; ++j) {
        int p = j * 1024 + t;
        float x = px[p], y = px[NPTS + p], z = px[2 * NPTS + p];
        lx[j] = x; ly[j] = y; lz[j] = z;
        pcL[p] = make_float4(x, y, z, 0.0f);
    }
    if (t < 3) keySlot[t] = 0ull;
    __syncthreads();

    float md[4] = {1e10f, 1e10f, 1e10f, 1e10f};
    float4 cc = pcL[0];
    int cur = 0;

    for (int it = 0; it < KREG; ++it) {
        if (t == 0) {
            outC[(size_t)b * 3 * KREG + it]            = cc.x;
            outC[(size_t)b * 3 * KREG + KREG + it]     = cc.y;
            outC[(size_t)b * 3 * KREG + 2 * KREG + it] = cc.z;
        }
        unsigned long long best = 0ull;
        #pragma unroll
        for (int j = 0; j < 4; ++j) {
            int p = j * 1024 + t;
            float dx = __fsub_rn(lx[j], cc.x);
            float dy = __fsub_rn(ly[j], cc.y);
            float dz = __fsub_rn(lz[j], cc.z);
            float d = __fadd_rn(__fadd_rn(__fmul_rn(dx, dx), __fmul_rn(dy, dy)),
                                __fmul_rn(dz, dz));
            float m = fminf(md[j], d);
            md[j] = m;
            unsigned long long key =
                ((unsigned long long)__float_as_uint(m) << 32) |
                (unsigned long long)(0xFFFFFFFFu - (unsigned)p);
            best = (key > best) ? key : best;
        }
        // wave-level max
        #pragma unroll
        for (int s = 32; s > 0; s >>= 1) {
            unsigned long long o = __shfl_xor(best, s, 64);
            best = (o > best) ? o : best;
        }
        int nxt = (cur == 2) ? 0 : cur + 1;
        if ((t & 63) == 0) atomicMax(&keySlot[cur], best);
        if (t == 0) keySlot[nxt] = 0ull;   // safe: slot nxt next written iter it+1,
                                           // its previous readers finished before B_{it-1}
        __syncthreads();
        unsigned long long win = keySlot[cur];
        int f = (int)(0xFFFFFFFFu - (unsigned)(win & 0xFFFFFFFFull));
        cc = pcL[f];
        cur = nxt;
    }
}

// ---------------------------------------------------------------------------
// Ball query: one wave per centroid. Exact f32 (c2+x2)-2*dot formula.
// Keeps first NS in-radius indices in ascending order; pads with first index.
// ---------------------------------------------------------------------------
__global__ __launch_bounds__(256) void ballquery_kernel(
    const float* __restrict__ pc, const float* __restrict__ outC,
    int* __restrict__ gidx)
{
    int gw = blockIdx.x * 4 + (threadIdx.x >> 6);
    int lane = threadIdx.x & 63;
    int b = gw >> 10;
    int k = gw & (KREG - 1);
    const float* px = pc + (size_t)b * 3 * NPTS;

    float cx = outC[(size_t)b * 3 * KREG + k];
    float cy = outC[(size_t)b * 3 * KREG + KREG + k];
    float cz = outC[(size_t)b * 3 * KREG + 2 * KREG + k];
    float c2 = __fadd_rn(__fadd_rn(__fmul_rn(cx, cx), __fmul_rn(cy, cy)),
                         __fmul_rn(cz, cz));
    const float r2 = 0.16f;
    int base = gw * NS;
    int cnt = 0;
    int firstidx = -1;

    for (int nb = 0; nb < NPTS / 64; ++nb) {
        int n = nb * 64 + lane;
        float x = px[n], y = px[NPTS + n], z = px[2 * NPTS + n];
        float x2 = __fadd_rn(__fadd_rn(__fmul_rn(x, x), __fmul_rn(y, y)),
                             __fmul_rn(z, z));
        float dt = __fadd_rn(__fadd_rn(__fmul_rn(cx, x), __fmul_rn(cy, y)),
                             __fmul_rn(cz, z));
        float sqd = __fsub_rn(__fadd_rn(c2, x2), __fmul_rn(2.0f, dt));
        bool pred = (sqd <= r2);
        unsigned long long mask = __ballot(pred);
        if (firstidx < 0 && mask) firstidx = nb * 64 + __ffsll((long long)mask) - 1;
        int pos = cnt + __popcll(mask & ((1ull << lane) - 1ull));
        if (pred && pos < NS) gidx[base + pos] = n;
        cnt += __popcll(mask);
        if (cnt >= NS) break;
    }
    if (lane >= cnt) gidx[base + lane] = firstidx;
}

// ---------------------------------------------------------------------------
// Gather grouped coords (planar (3,P)) + 3x3 second-moment partials for BN1.
// ---------------------------------------------------------------------------
__global__ __launch_bounds__(256) void gather_kernel(
    const float* __restrict__ pc, const float* __restrict__ outC,
    const int* __restrict__ gidx, float* __restrict__ X0,
    float* __restrict__ mpart)
{
    float a[9] = {0, 0, 0, 0, 0, 0, 0, 0, 0};
    for (int p = blockIdx.x * 256 + threadIdx.x; p < PTOT; p += GATH_BLOCKS * 256) {
        int bk = p >> 6;
        int b = bk >> 10;
        int k = bk & (KREG - 1);
        int idx = gidx[p];
        const float* px = pc + (size_t)b * 3 * NPTS;
        float x = px[idx]            - outC[(size_t)b * 3 * KREG + k];
        float y = px[NPTS + idx]     - outC[(size_t)b * 3 * KREG + KREG + k];
        float z = px[2 * NPTS + idx] - outC[(size_t)b * 3 * KREG + 2 * KREG + k];
        X0[p] = x; X0[PTOT + p] = y; X0[2 * PTOT + p] = z;
        a[0] += x;     a[1] += y;     a[2] += z;
        a[3] += x * x; a[4] += y * y; a[5] += z * z;
        a[6] += x * y; a[7] += x * z; a[8] += y * z;
    }
    __shared__ float red[4][9];
    int wv = threadIdx.x >> 6;
    #pragma unroll
    for (int q = 0; q < 9; ++q) {
        float v = a[q];
        #pragma unroll
        for (int s = 32; s > 0; s >>= 1) v += __shfl_xor(v, s, 64);
        if ((threadIdx.x & 63) == 0) red[wv][q] = v;
    }
    __syncthreads();
    if (threadIdx.x < 9) {
        mpart[blockIdx.x * 9 + threadIdx.x] =
            red[0][threadIdx.x] + red[1][threadIdx.x] +
            red[2][threadIdx.x] + red[3][threadIdx.x];
    }
}

// ---------------------------------------------------------------------------
// BN1 params analytically from moments: y1 = W1 x + b1 is linear in x.
// ---------------------------------------------------------------------------
__global__ void bn1_finalize(
    const float* __restrict__ mpart, const float* __restrict__ w1,
    const float* __restrict__ b1, const float* __restrict__ g1,
    const float* __restrict__ be1, float* __restrict__ sc1,
    float* __restrict__ sh1)
{
    __shared__ double M[9];
    int t = threadIdx.x;
    if (t < 9) {
        double s = 0;
        for (int i = 0; i < GATH_BLOCKS; ++i) s += (double)mpart[i * 9 + t];
        M[t] = s / (double)PTOT;
    }
    __syncthreads();
    if (t < 64) {
        double mux = M[0], muy = M[1], muz = M[2];
        double xx = M[3], yy = M[4], zz = M[5], xy = M[6], xz = M[7], yz = M[8];
        double wx = w1[t * 3], wy = w1[t * 3 + 1], wz = w1[t * 3 + 2], bb = b1[t];
        double wmu = wx * mux + wy * muy + wz * muz;
        double mean = wmu + bb;
        double ey2 = wx * wx * xx + wy * wy * yy + wz * wz * zz
                   + 2.0 * (wx * wy * xy + wx * wz * xz + wy * wz * yz)
                   + 2.0 * bb * wmu + bb * bb;
        double var = ey2 - mean * mean;
        double scale = (double)g1[t] / sqrt(var + 1e-5);
        sc1[t] = (float)scale;
        sh1[t] = (float)((double)be1[t] - mean * scale);
    }
}

// ---------------------------------------------------------------------------
// Transpose small weight matrices so conv loops read contiguous (-> s_load).
// ---------------------------------------------------------------------------
__global__ __launch_bounds__(256) void prep_kernel(
    const float* __restrict__ w2, const float* __restrict__ w3,
    float* __restrict__ w2t, float* __restrict__ w3t)
{
    int t = blockIdx.x * 256 + threadIdx.x;
    if (t < 4096) w2t[(t & 63) * 64 + (t >> 6)] = w2[t];
    if (t < 8192) w3t[(t & 63) * 128 + (t >> 6)] = w3[t];
}

// ---------------------------------------------------------------------------
// Pass A: conv1+BN1+ReLU -> conv2, accumulate per-channel sum/sumsq of y2.
// 128 threads/block, 1 position/thread. Activations in LDS columns.
// ---------------------------------------------------------------------------
__global__ __launch_bounds__(128) void conv12_stats_kernel(
    const float* __restrict__ X0,
    const float* __restrict__ w1, const float* __restrict__ b1,
    const float* __restrict__ sc1, const float* __restrict__ sh1,
    const float* __restrict__ w2t, const float* __restrict__ b2,
    float* __restrict__ sum2, float* __restrict__ sq2)
{
    __shared__ float xbuf[64 * 128];
    __shared__ float trans[2][8][65];
    const int t = threadIdx.x;
    const int p = blockIdx.x * 128 + t;

    float x = X0[p], y = X0[PTOT + p], z = X0[2 * PTOT + p];
    #pragma unroll
    for (int o = 0; o < 64; ++o) {
        float v = b1[o];
        v = fmaf(w1[o * 3 + 2], z, v);
        v = fmaf(w1[o * 3 + 1], y, v);
        v = fmaf(w1[o * 3 + 0], x, v);
        v = fmaf(v, sc1[o], sh1[o]);
        xbuf[o * 128 + t] = fmaxf(v, 0.0f);
    }
    float acc[64];
    #pragma unroll
    for (int o = 0; o < 64; ++o) acc[o] = b2[o];
    for (int c = 0; c < 64; ++c) {
        float xv = xbuf[c * 128 + t];
        #pragma unroll
        for (int o = 0; o < 64; ++o) acc[o] = fmaf(w2t[c * 64 + o], xv, acc[o]);
    }
    const int wv = t >> 6, lane = t & 63;
    const int gw = blockIdx.x * 2 + wv;
    #pragma unroll
    for (int ch = 0; ch < 8; ++ch) {
        __syncthreads();
        #pragma unroll
        for (int o = 0; o < 8; ++o) trans[wv][o][lane] = acc[ch * 8 + o];
        __syncthreads();
        int row = lane >> 3, seg = lane & 7;
        float s = 0.f, q = 0.f;
        #pragma unroll
        for (int j = 0; j < 8; ++j) {
            float v = trans[wv][row][seg * 8 + j];
            s += v; q = fmaf(v, v, q);
        }
        s += __shfl_xor(s, 1, 64); q += __shfl_xor(q, 1, 64);
        s += __shfl_xor(s, 2, 64); q += __shfl_xor(q, 2, 64);
        s += __shfl_xor(s, 4, 64); q += __shfl_xor(q, 4, 64);
        if (seg == 0) {
            int o = ch * 8 + row;
            sum2[(size_t)o * NWAVE + gw] = s;
            sq2[(size_t)o * NWAVE + gw] = q;
        }
    }
}

// ---------------------------------------------------------------------------
// Generic BN finalize: per-channel block sums wave partials (f64), emits
// scale/shift.
// ---------------------------------------------------------------------------
__global__ __launch_bounds__(256) void bn_finalize_kernel(
    const float* __restrict__ sumb, const float* __restrict__ sqb,
    const float* __restrict__ g, const float* __restrict__ be,
    float* __restrict__ sc, float* __restrict__ sh)
{
    int o = blockIdx.x, t = threadIdx.x;
    double s = 0, q = 0;
    for (int i = t; i < NWAVE; i += 256) {
        s += (double)sumb[(size_t)o * NWAVE + i];
        q += (double)sqb[(size_t)o * NWAVE + i];
    }
    #pragma unroll
    for (int m = 32; m > 0; m >>= 1) {
        s += __shfl_xor(s, m, 64);
        q += __shfl_xor(q, m, 64);
    }
    __shared__ double rs[4], rq[4];
    if ((t & 63) == 0) { rs[t >> 6] = s; rq[t >> 6] = q; }
    __syncthreads();
    if (t == 0) {
        s = rs[0] + rs[1] + rs[2] + rs[3];
        q = rq[0] + rq[1] + rq[2] + rq[3];
        double mean = s / (double)PTOT;
        double var = q / (double)PTOT - mean * mean;
        double scale = (double)g[o] / sqrt(var + 1e-5);
        sc[o] = (float)scale;
        sh[o] = (float)((double)be[o] - mean * scale);
    }
}

// ---------------------------------------------------------------------------
// Pass B: recompute conv1->conv2 (BN params now known), conv3; emit per-(bk,o)
// max/min of y3 plus per-channel sum/sumsq partials. y3 never stored.
// ---------------------------------------------------------------------------
__global__ __launch_bounds__(128) void conv123_kernel(
    const float* __restrict__ X0,
    const float* __restrict__ w1, const float* __restrict__ b1,
    const float* __restrict__ sc1, const float* __restrict__ sh1,
    const float* __restrict__ w2t, const float* __restrict__ b2,
    const float* __restrict__ sc2, const float* __restrict__ sh2,
    const float* __restrict__ w3t, const float* __restrict__ b3,
    float* __restrict__ y3max, float* __restrict__ y3min,
    float* __restrict__ sum3, float* __restrict__ sq3)
{
    __shared__ float xbuf[64 * 128];
    __shared__ float trans[2][8][65];
    const int t = threadIdx.x;
    const int p = blockIdx.x * 128 + t;

    float x = X0[p], y = X0[PTOT + p], z = X0[2 * PTOT + p];
    #pragma unroll
    for (int o = 0; o < 64; ++o) {
        float v = b1[o];
        v = fmaf(w1[o * 3 + 2], z, v);
        v = fmaf(w1[o * 3 + 1], y, v);
        v = fmaf(w1[o * 3 + 0], x, v);
        v = fmaf(v, sc1[o], sh1[o]);
        xbuf[o * 128 + t] = fmaxf(v, 0.0f);
    }
    float acc2[64];
    #pragma unroll
    for (int o = 0; o < 64; ++o) acc2[o] = b2[o];
    for (int c = 0; c < 64; ++c) {
        float xv = xbuf[c * 128 + t];
        #pragma unroll
        for (int o = 0; o < 64; ++o) acc2[o] = fmaf(w2t[c * 64 + o], xv, acc2[o]);
    }
    #pragma unroll
    for (int o = 0; o < 64; ++o) {
        xbuf[o * 128 + t] = fmaxf(fmaf(acc2[o], sc2[o], sh2[o]), 0.0f);
    }
    float acc3[128];
    #pragma unroll
    for (int o = 0; o < 128; ++o) acc3[o] = b3[o];
    for (int c = 0; c < 64; ++c) {
        float xv = xbuf[c * 128 + t];
        #pragma unroll
        for (int o = 0; o < 128; ++o) acc3[o] = fmaf(w3t[c * 128 + o], xv, acc3[o]);
    }
    const int wv = t >> 6, lane = t & 63;
    const int gw = blockIdx.x * 2 + wv;   // == bk (group) index
    #pragma unroll
    for (int ch = 0; ch < 16; ++ch) {
        __syncthreads();
        #pragma unroll
        for (int o = 0; o < 8; ++o) trans[wv][o][lane] = acc3[ch * 8 + o];
        __syncthreads();
        int row = lane >> 3, seg = lane & 7;
        float s = 0.f, q = 0.f, mx = -1e30f, mn = 1e30f;
        #pragma unroll
        for (int j = 0; j < 8; ++j) {
            float v = trans[wv][row][seg * 8 + j];
            s += v; q = fmaf(v, v, q);
            mx = fmaxf(mx, v); mn = fminf(mn, v);
        }
        s += __shfl_xor(s, 1, 64); q += __shfl_xor(q, 1, 64);
        mx = fmaxf(mx, __shfl_xor(mx, 1, 64)); mn = fminf(mn, __shfl_xor(mn, 1, 64));
        s += __shfl_xor(s, 2, 64); q += __shfl_xor(q, 2, 64);
        mx = fmaxf(mx, __shfl_xor(mx, 2, 64)); mn = fminf(mn, __shfl_xor(mn, 2, 64));
        s += __shfl_xor(s, 4, 64); q += __shfl_xor(q, 4, 64);
        mx = fmaxf(mx, __shfl_xor(mx, 4, 64)); mn = fminf(mn, __shfl_xor(mn, 4, 64));
        if (seg == 0) {
            int o = ch * 8 + row;
            y3max[(size_t)gw * 128 + o] = mx;
            y3min[(size_t)gw * 128 + o] = mn;
            sum3[(size_t)o * NWAVE + gw] = s;
            sq3[(size_t)o * NWAVE + gw] = q;
        }
    }
}

// ---------------------------------------------------------------------------
// Final: feats[b,o,k] = relu(scale3*extreme + shift3), transposed via LDS.
// max over samples commutes with the monotone BN+ReLU (min if scale<0).
// ---------------------------------------------------------------------------
__global__ __launch_bounds__(256) void feats_kernel(
    const float* __restrict__ y3max, const float* __restrict__ y3min,
    const float* __restrict__ sc3, const float* __restrict__ sh3,
    float* __restrict__ feats)
{
    __shared__ float tile[64][129];
    int blk = blockIdx.x;          // b*16 + kt
    int b = blk >> 4, kt = blk & 15;
    int t = threadIdx.x;
    size_t bk0 = (size_t)(b * KREG + kt * 64);
    #pragma unroll
    for (int i = 0; i < 32; ++i) {
        int idx = i * 256 + t;
        int o = idx & 127, kk = idx >> 7;
        float a = sc3[o];
        float v = (a >= 0.f) ? y3max[(bk0 + kk) * 128 + o]
                             : y3min[(bk0 + kk) * 128 + o];
        tile[kk][o] = fmaxf(fmaf(v, a, sh3[o]), 0.0f);
    }
    __syncthreads();
    #pragma unroll
    for (int i = 0; i < 32; ++i) {
        int idx = i * 256 + t;
        int kk = idx & 63, o = idx >> 6;
        feats[(size_t)b * 128 * KREG + (size_t)o * KREG + kt * 64 + kk] = tile[kk][o];
    }
}

// ---------------------------------------------------------------------------
extern "C" void kernel_launch(void* const* d_in, const int* in_sizes, int n_in,
                              void* d_out, int out_size, void* d_ws, size_t ws_size,
                              hipStream_t stream)
{
    const float* pc  = (const float*)d_in[0];
    const float* w1  = (const float*)d_in[1];
    const float* b1  = (const float*)d_in[2];
    const float* g1  = (const float*)d_in[3];
    const float* be1 = (const float*)d_in[4];
    const float* w2  = (const float*)d_in[5];
    const float* b2  = (const float*)d_in[6];
    const float* g2  = (const float*)d_in[7];
    const float* be2 = (const float*)d_in[8];
    const float* w3  = (const float*)d_in[9];
    const float* b3  = (const float*)d_in[10];
    const float* g3  = (const float*)d_in[11];
    const float* be3 = (const float*)d_in[12];

    float* outC  = (float*)d_out;                      // (16,3,1024)
    float* feats = (float*)d_out + NB * 3 * KREG;      // (16,128,1024)

    const size_t MB = 1024 * 1024;
    char* ws = (char*)d_ws;
    int*   gidx  = (int*)ws;                           // 4 MB
    float* X0    = (float*)(ws + 4 * MB);              // 12 MB (3 x P)
    float* mpart = (float*)(ws + 16 * MB);             // 9216 B
    float* sc1   = (float*)(ws + 16 * MB + 16 * 1024);
    float* sh1   = (float*)(ws + 16 * MB + 17 * 1024);
    float* sc2   = (float*)(ws + 16 * MB + 18 * 1024);
    float* sh2   = (float*)(ws + 16 * MB + 19 * 1024);
    float* sc3   = (float*)(ws + 16 * MB + 20 * 1024);
    float* sh3   = (float*)(ws + 16 * MB + 21 * 1024);
    float* w2t   = (float*)(ws + 16 * MB + 32 * 1024); // 16 KB
    float* w3t   = (float*)(ws + 16 * MB + 64 * 1024); // 32 KB
    float* sum2  = (float*)(ws + 17 * MB);             // 4 MB
    float* sq2   = (float*)(ws + 21 * MB);             // 4 MB
    float* sum3  = (float*)(ws + 25 * MB);             // 8 MB
    float* sq3   = (float*)(ws + 33 * MB);             // 8 MB
    float* y3max = (float*)(ws + 41 * MB);             // 8 MB
    float* y3min = (float*)(ws + 49 * MB);             // 8 MB

    fps_kernel<<<NB, 1024, 0, stream>>>(pc, outC);
    ballquery_kernel<<<(NB * KREG) / 4, 256, 0, stream>>>(pc, outC, gidx);
    gather_kernel<<<GATH_BLOCKS, 256, 0, stream>>>(pc, outC, gidx, X0, mpart);
    bn1_finalize<<<1, 64, 0, stream>>>(mpart, w1, b1, g1, be1, sc1, sh1);
    prep_kernel<<<32, 256, 0, stream>>>(w2, w3, w2t, w3t);
    conv12_stats_kernel<<<PTOT / 128, 128, 0, stream>>>(
        X0, w1, b1, sc1, sh1, w2t, b2, sum2, sq2);
    bn_finalize_kernel<<<64, 256, 0, stream>>>(sum2, sq2, g2, be2, sc2, sh2);
    conv123_kernel<<<PTOT / 128, 128, 0, stream>>>(
        X0, w1, b1, sc1, sh1, w2t, b2, sc2, sh2, w3t, b3,
        y3max, y3min, sum3, sq3);
    bn_finalize_kernel<<<128, 256, 0, stream>>>(sum3, sq3, g3, be3, sc3, sh3);
    feats_kernel<<<NB * (KREG / 64), 256, 0, stream>>>(y3max, y3min, sc3, sh3, feats);
}

// Round 4
// 1379.971 us; speedup vs baseline: 1.3862x; 1.1720x over previous
//
#include <hip/hip_runtime.h>
#include <stdint.h>

#define NPTS 4096
#define KREG 1024
#define NS   64
#define NB   16
#define PTOT (NB*KREG*NS)        // 1048576 positions
#define NWAVE (PTOT/64)          // 16384
#define GATH_BLOCKS 256

// ---------------------------------------------------------------------------
// Wave-wide reductions with DPP (VALU) for strides 1..8, shfl for 16/32.
// ---------------------------------------------------------------------------
__device__ __forceinline__ float wave_max_f32(float v) {
    int x;
    x = __builtin_amdgcn_mov_dpp(__float_as_int(v), 0xB1, 0xF, 0xF, true);  // quad_perm xor1
    v = fmaxf(v, __int_as_float(x));
    x = __builtin_amdgcn_mov_dpp(__float_as_int(v), 0x4E, 0xF, 0xF, true);  // quad_perm xor2
    v = fmaxf(v, __int_as_float(x));
    x = __builtin_amdgcn_mov_dpp(__float_as_int(v), 0x141, 0xF, 0xF, true); // row_half_mirror
    v = fmaxf(v, __int_as_float(x));
    x = __builtin_amdgcn_mov_dpp(__float_as_int(v), 0x140, 0xF, 0xF, true); // row_mirror
    v = fmaxf(v, __int_as_float(x));
    v = fmaxf(v, __shfl_xor(v, 16, 64));
    v = fmaxf(v, __shfl_xor(v, 32, 64));
    return v;
}

__device__ __forceinline__ unsigned wave_min_u32(unsigned v) {
    unsigned x;
    x = (unsigned)__builtin_amdgcn_mov_dpp((int)v, 0xB1, 0xF, 0xF, true);
    v = (x < v) ? x : v;
    x = (unsigned)__builtin_amdgcn_mov_dpp((int)v, 0x4E, 0xF, 0xF, true);
    v = (x < v) ? x : v;
    x = (unsigned)__builtin_amdgcn_mov_dpp((int)v, 0x141, 0xF, 0xF, true);
    v = (x < v) ? x : v;
    x = (unsigned)__builtin_amdgcn_mov_dpp((int)v, 0x140, 0xF, 0xF, true);
    v = (x < v) ? x : v;
    x = (unsigned)__shfl_xor((int)v, 16, 64);
    v = (x < v) ? x : v;
    x = (unsigned)__shfl_xor((int)v, 32, 64);
    v = (x < v) ? x : v;
    return v;
}

// ---------------------------------------------------------------------------
// FPS: one block per batch, 256 threads (4 waves), 16 points/thread in
// REGISTERS. Exact f32 (no FMA) to match numpy reference. Argmax with
// first-index tie-break done in two exact phases: (1) wave max of f32
// min-dist (DPP, VALU-only for strides 1..8), (2) wave min of candidate
// index among lanes holding the max. Cross-wave combine via parity-slot
// LDS (4 u64 keys), one barrier per iteration, winner computed redundantly
// by every thread (uniform). Writes centroids (B,3,K) directly into d_out.
// ---------------------------------------------------------------------------
__global__ __launch_bounds__(256) void fps_kernel(
    const float* __restrict__ pc, float* __restrict__ outC)
{
    __shared__ float4 pcL[NPTS];                 // 64 KB
    __shared__ unsigned long long wpart[2][4];

    const int b = blockIdx.x;
    const int t = threadIdx.x;
    const int wv = t >> 6;
    const float* px = pc + (size_t)b * 3 * NPTS;

    float lx[16], ly[16], lz[16], md[16];
    #pragma unroll
    for (int j = 0; j < 16; ++j) {
        int p = j * 256 + t;
        float x = px[p], y = px[NPTS + p], z = px[2 * NPTS + p];
        lx[j] = x; ly[j] = y; lz[j] = z;
        pcL[p] = make_float4(x, y, z, 0.0f);
        md[j] = 1e10f;
    }
    __syncthreads();
    float4 cc = pcL[0];

    for (int it = 0; it < KREG; ++it) {
        if (t == 0) {
            outC[(size_t)b * 3 * KREG + it]            = cc.x;
            outC[(size_t)b * 3 * KREG + KREG + it]     = cc.y;
            outC[(size_t)b * 3 * KREG + 2 * KREG + it] = cc.z;
        }
        float mbest = -1.0f;
        int jbest = 0;
        #pragma unroll
        for (int j = 0; j < 16; ++j) {
            float dx = __fsub_rn(lx[j], cc.x);
            float dy = __fsub_rn(ly[j], cc.y);
            float dz = __fsub_rn(lz[j], cc.z);
            float d = __fadd_rn(__fadd_rn(__fmul_rn(dx, dx), __fmul_rn(dy, dy)),
                                __fmul_rn(dz, dz));
            float m = fminf(md[j], d);
            md[j] = m;
            if (m > mbest) { mbest = m; jbest = j; }   // first j wins ties -> min p
        }
        // Phase 1: wave max of min-dist (exact, no FP arithmetic change)
        float mx = wave_max_f32(mbest);
        // Phase 2: wave min index among lanes achieving mx
        unsigned pl = (mbest == mx) ? (unsigned)(jbest * 256 + t) : 0xFFFFFFFFu;
        unsigned pmin = wave_min_u32(pl);

        unsigned long long key =
            ((unsigned long long)__float_as_uint(mx) << 32) |
            (unsigned long long)(0xFFFFFFFFu - pmin);
        if ((t & 63) == 0) wpart[it & 1][wv] = key;
        __syncthreads();
        unsigned long long k0 = wpart[it & 1][0];
        unsigned long long k1 = wpart[it & 1][1];
        unsigned long long k2 = wpart[it & 1][2];
        unsigned long long k3 = wpart[it & 1][3];
        unsigned long long ka = (k0 > k1) ? k0 : k1;
        unsigned long long kb = (k2 > k3) ? k2 : k3;
        unsigned long long kk = (ka > kb) ? ka : kb;
        int f = (int)(0xFFFFFFFFu - (unsigned)(kk & 0xFFFFFFFFull));
        cc = pcL[f];
    }
}

// ---------------------------------------------------------------------------
// Ball query: one wave per centroid. Exact f32 (c2+x2)-2*dot formula.
// Keeps first NS in-radius indices in ascending order; pads with first index.
// ---------------------------------------------------------------------------
__global__ __launch_bounds__(256) void ballquery_kernel(
    const float* __restrict__ pc, const float* __restrict__ outC,
    int* __restrict__ gidx)
{
    int gw = blockIdx.x * 4 + (threadIdx.x >> 6);
    int lane = threadIdx.x & 63;
    int b = gw >> 10;
    int k = gw & (KREG - 1);
    const float* px = pc + (size_t)b * 3 * NPTS;

    float cx = outC[(size_t)b * 3 * KREG + k];
    float cy = outC[(size_t)b * 3 * KREG + KREG + k];
    float cz = outC[(size_t)b * 3 * KREG + 2 * KREG + k];
    float c2 = __fadd_rn(__fadd_rn(__fmul_rn(cx, cx), __fmul_rn(cy, cy)),
                         __fmul_rn(cz, cz));
    const float r2 = 0.16f;
    int base = gw * NS;
    int cnt = 0;
    int firstidx = -1;

    for (int nb = 0; nb < NPTS / 64; ++nb) {
        int n = nb * 64 + lane;
        float x = px[n], y = px[NPTS + n], z = px[2 * NPTS + n];
        float x2 = __fadd_rn(__fadd_rn(__fmul_rn(x, x), __fmul_rn(y, y)),
                             __fmul_rn(z, z));
        float dt = __fadd_rn(__fadd_rn(__fmul_rn(cx, x), __fmul_rn(cy, y)),
                             __fmul_rn(cz, z));
        float sqd = __fsub_rn(__fadd_rn(c2, x2), __fmul_rn(2.0f, dt));
        bool pred = (sqd <= r2);
        unsigned long long mask = __ballot(pred);
        if (firstidx < 0 && mask) firstidx = nb * 64 + __ffsll((long long)mask) - 1;
        int pos = cnt + __popcll(mask & ((1ull << lane) - 1ull));
        if (pred && pos < NS) gidx[base + pos] = n;
        cnt += __popcll(mask);
        if (cnt >= NS) break;
    }
    if (lane >= cnt) gidx[base + lane] = firstidx;
}

// ---------------------------------------------------------------------------
// Gather grouped coords (planar (3,P)) + 3x3 second-moment partials for BN1.
// ---------------------------------------------------------------------------
__global__ __launch_bounds__(256) void gather_kernel(
    const float* __restrict__ pc, const float* __restrict__ outC,
    const int* __restrict__ gidx, float* __restrict__ X0,
    float* __restrict__ mpart)
{
    float a[9] = {0, 0, 0, 0, 0, 0, 0, 0, 0};
    for (int p = blockIdx.x * 256 + threadIdx.x; p < PTOT; p += GATH_BLOCKS * 256) {
        int bk = p >> 6;
        int b = bk >> 10;
        int k = bk & (KREG - 1);
        int idx = gidx[p];
        const float* px = pc + (size_t)b * 3 * NPTS;
        float x = px[idx]            - outC[(size_t)b * 3 * KREG + k];
        float y = px[NPTS + idx]     - outC[(size_t)b * 3 * KREG + KREG + k];
        float z = px[2 * NPTS + idx] - outC[(size_t)b * 3 * KREG + 2 * KREG + k];
        X0[p] = x; X0[PTOT + p] = y; X0[2 * PTOT + p] = z;
        a[0] += x;     a[1] += y;     a[2] += z;
        a[3] += x * x; a[4] += y * y; a[5] += z * z;
        a[6] += x * y; a[7] += x * z; a[8] += y * z;
    }
    __shared__ float red[4][9];
    int wv = threadIdx.x >> 6;
    #pragma unroll
    for (int q = 0; q < 9; ++q) {
        float v = a[q];
        #pragma unroll
        for (int s = 32; s > 0; s >>= 1) v += __shfl_xor(v, s, 64);
        if ((threadIdx.x & 63) == 0) red[wv][q] = v;
    }
    __syncthreads();
    if (threadIdx.x < 9) {
        mpart[blockIdx.x * 9 + threadIdx.x] =
            red[0][threadIdx.x] + red[1][threadIdx.x] +
            red[2][threadIdx.x] + red[3][threadIdx.x];
    }
}

// ---------------------------------------------------------------------------
// BN1 params analytically from moments: y1 = W1 x + b1 is linear in x.
// ---------------------------------------------------------------------------
__global__ void bn1_finalize(
    const float* __restrict__ mpart, const float* __restrict__ w1,
    const float* __restrict__ b1, const float* __restrict__ g1,
    const float* __restrict__ be1, float* __restrict__ sc1,
    float* __restrict__ sh1)
{
    __shared__ double M[9];
    int t = threadIdx.x;
    if (t < 9) {
        double s = 0;
        for (int i = 0; i < GATH_BLOCKS; ++i) s += (double)mpart[i * 9 + t];
        M[t] = s / (double)PTOT;
    }
    __syncthreads();
    if (t < 64) {
        double mux = M[0], muy = M[1], muz = M[2];
        double xx = M[3], yy = M[4], zz = M[5], xy = M[6], xz = M[7], yz = M[8];
        double wx = w1[t * 3], wy = w1[t * 3 + 1], wz = w1[t * 3 + 2], bb = b1[t];
        double wmu = wx * mux + wy * muy + wz * muz;
        double mean = wmu + bb;
        double ey2 = wx * wx * xx + wy * wy * yy + wz * wz * zz
                   + 2.0 * (wx * wy * xy + wx * wz * xz + wy * wz * yz)
                   + 2.0 * bb * wmu + bb * bb;
        double var = ey2 - mean * mean;
        double scale = (double)g1[t] / sqrt(var + 1e-5);
        sc1[t] = (float)scale;
        sh1[t] = (float)((double)be1[t] - mean * scale);
    }
}

// ---------------------------------------------------------------------------
// Transpose small weight matrices so conv loops read contiguous (-> s_load).
// ---------------------------------------------------------------------------
__global__ __launch_bounds__(256) void prep_kernel(
    const float* __restrict__ w2, const float* __restrict__ w3,
    float* __restrict__ w2t, float* __restrict__ w3t)
{
    int t = blockIdx.x * 256 + threadIdx.x;
    if (t < 4096) w2t[(t & 63) * 64 + (t >> 6)] = w2[t];
    if (t < 8192) w3t[(t & 63) * 128 + (t >> 6)] = w3[t];
}

// ---------------------------------------------------------------------------
// Pass A: conv1+BN1+ReLU -> conv2, accumulate per-channel sum/sumsq of y2.
// 128 threads/block, 1 position/thread. Activations in LDS columns.
// ---------------------------------------------------------------------------
__global__ __launch_bounds__(128) void conv12_stats_kernel(
    const float* __restrict__ X0,
    const float* __restrict__ w1, const float* __restrict__ b1,
    const float* __restrict__ sc1, const float* __restrict__ sh1,
    const float* __restrict__ w2t, const float* __restrict__ b2,
    float* __restrict__ sum2, float* __restrict__ sq2)
{
    __shared__ float xbuf[64 * 128];
    __shared__ float trans[2][8][65];
    const int t = threadIdx.x;
    const int p = blockIdx.x * 128 + t;

    float x = X0[p], y = X0[PTOT + p], z = X0[2 * PTOT + p];
    #pragma unroll
    for (int o = 0; o < 64; ++o) {
        float v = b1[o];
        v = fmaf(w1[o * 3 + 2], z, v);
        v = fmaf(w1[o * 3 + 1], y, v);
        v = fmaf(w1[o * 3 + 0], x, v);
        v = fmaf(v, sc1[o], sh1[o]);
        xbuf[o * 128 + t] = fmaxf(v, 0.0f);
    }
    float acc[64];
    #pragma unroll
    for (int o = 0; o < 64; ++o) acc[o] = b2[o];
    for (int c = 0; c < 64; ++c) {
        float xv = xbuf[c * 128 + t];
        #pragma unroll
        for (int o = 0; o < 64; ++o) acc[o] = fmaf(w2t[c * 64 + o], xv, acc[o]);
    }
    const int wv = t >> 6, lane = t & 63;
    const int gw = blockIdx.x * 2 + wv;
    #pragma unroll
    for (int ch = 0; ch < 8; ++ch) {
        __syncthreads();
        #pragma unroll
        for (int o = 0; o < 8; ++o) trans[wv][o][lane] = acc[ch * 8 + o];
        __syncthreads();
        int row = lane >> 3, seg = lane & 7;
        float s = 0.f, q = 0.f;
        #pragma unroll
        for (int j = 0; j < 8; ++j) {
            float v = trans[wv][row][seg * 8 + j];
            s += v; q = fmaf(v, v, q);
        }
        s += __shfl_xor(s, 1, 64); q += __shfl_xor(q, 1, 64);
        s += __shfl_xor(s, 2, 64); q += __shfl_xor(q, 2, 64);
        s += __shfl_xor(s, 4, 64); q += __shfl_xor(q, 4, 64);
        if (seg == 0) {
            int o = ch * 8 + row;
            sum2[(size_t)o * NWAVE + gw] = s;
            sq2[(size_t)o * NWAVE + gw] = q;
        }
    }
}

// ---------------------------------------------------------------------------
// Generic BN finalize: per-channel block sums wave partials (f64), emits
// scale/shift.
// ---------------------------------------------------------------------------
__global__ __launch_bounds__(256) void bn_finalize_kernel(
    const float* __restrict__ sumb, const float* __restrict__ sqb,
    const float* __restrict__ g, const float* __restrict__ be,
    float* __restrict__ sc, float* __restrict__ sh)
{
    int o = blockIdx.x, t = threadIdx.x;
    double s = 0, q = 0;
    for (int i = t; i < NWAVE; i += 256) {
        s += (double)sumb[(size_t)o * NWAVE + i];
        q += (double)sqb[(size_t)o * NWAVE + i];
    }
    #pragma unroll
    for (int m = 32; m > 0; m >>= 1) {
        s += __shfl_xor(s, m, 64);
        q += __shfl_xor(q, m, 64);
    }
    __shared__ double rs[4], rq[4];
    if ((t & 63) == 0) { rs[t >> 6] = s; rq[t >> 6] = q; }
    __syncthreads();
    if (t == 0) {
        s = rs[0] + rs[1] + rs[2] + rs[3];
        q = rq[0] + rq[1] + rq[2] + rq[3];
        double mean = s / (double)PTOT;
        double var = q / (double)PTOT - mean * mean;
        double scale = (double)g[o] / sqrt(var + 1e-5);
        sc[o] = (float)scale;
        sh[o] = (float)((double)be[o] - mean * scale);
    }
}

// ---------------------------------------------------------------------------
// Pass B: recompute conv1->conv2 (BN params now known), conv3; emit per-(bk,o)
// max/min of y3 plus per-channel sum/sumsq partials. y3 never stored.
// ---------------------------------------------------------------------------
__global__ __launch_bounds__(128) void conv123_kernel(
    const float* __restrict__ X0,
    const float* __restrict__ w1, const float* __restrict__ b1,
    const float* __restrict__ sc1, const float* __restrict__ sh1,
    const float* __restrict__ w2t, const float* __restrict__ b2,
    const float* __restrict__ sc2, const float* __restrict__ sh2,
    const float* __restrict__ w3t, const float* __restrict__ b3,
    float* __restrict__ y3max, float* __restrict__ y3min,
    float* __restrict__ sum3, float* __restrict__ sq3)
{
    __shared__ float xbuf[64 * 128];
    __shared__ float trans[2][8][65];
    const int t = threadIdx.x;
    const int p = blockIdx.x * 128 + t;

    float x = X0[p], y = X0[PTOT + p], z = X0[2 * PTOT + p];
    #pragma unroll
    for (int o = 0; o < 64; ++o) {
        float v = b1[o];
        v = fmaf(w1[o * 3 + 2], z, v);
        v = fmaf(w1[o * 3 + 1], y, v);
        v = fmaf(w1[o * 3 + 0], x, v);
        v = fmaf(v, sc1[o], sh1[o]);
        xbuf[o * 128 + t] = fmaxf(v, 0.0f);
    }
    float acc2[64];
    #pragma unroll
    for (int o = 0; o < 64; ++o) acc2[o] = b2[o];
    for (int c = 0; c < 64; ++c) {
        float xv = xbuf[c * 128 + t];
        #pragma unroll
        for (int o = 0; o < 64; ++o) acc2[o] = fmaf(w2t[c * 64 + o], xv, acc2[o]);
    }
    #pragma unroll
    for (int o = 0; o < 64; ++o) {
        xbuf[o * 128 + t] = fmaxf(fmaf(acc2[o], sc2[o], sh2[o]), 0.0f);
    }
    float acc3[128];
    #pragma unroll
    for (int o = 0; o < 128; ++o) acc3[o] = b3[o];
    for (int c = 0; c < 64; ++c) {
        float xv = xbuf[c * 128 + t];
        #pragma unroll
        for (int o = 0; o < 128; ++o) acc3[o] = fmaf(w3t[c * 128 + o], xv, acc3[o]);
    }
    const int wv = t >> 6, lane = t & 63;
    const int gw = blockIdx.x * 2 + wv;   // == bk (group) index
    #pragma unroll
    for (int ch = 0; ch < 16; ++ch) {
        __syncthreads();
        #pragma unroll
        for (int o = 0; o < 8; ++o) trans[wv][o][lane] = acc3[ch * 8 + o];
        __syncthreads();
        int row = lane >> 3, seg = lane & 7;
        float s = 0.f, q = 0.f, mx = -1e30f, mn = 1e30f;
        #pragma unroll
        for (int j = 0; j < 8; ++j) {
            float v = trans[wv][row][seg * 8 + j];
            s += v; q = fmaf(v, v, q);
            mx = fmaxf(mx, v); mn = fminf(mn, v);
        }
        s += __shfl_xor(s, 1, 64); q += __shfl_xor(q, 1, 64);
        mx = fmaxf(mx, __shfl_xor(mx, 1, 64)); mn = fminf(mn, __shfl_xor(mn, 1, 64));
        s += __shfl_xor(s, 2, 64); q += __shfl_xor(q, 2, 64);
        mx = fmaxf(mx, __shfl_xor(mx, 2, 64)); mn = fminf(mn, __shfl_xor(mn, 2, 64));
        s += __shfl_xor(s, 4, 64); q += __shfl_xor(q, 4, 64);
        mx = fmaxf(mx, __shfl_xor(mx, 4, 64)); mn = fminf(mn, __shfl_xor(mn, 4, 64));
        if (seg == 0) {
            int o = ch * 8 + row;
            y3max[(size_t)gw * 128 + o] = mx;
            y3min[(size_t)gw * 128 + o] = mn;
            sum3[(size_t)o * NWAVE + gw] = s;
            sq3[(size_t)o * NWAVE + gw] = q;
        }
    }
}

// ---------------------------------------------------------------------------
// Final: feats[b,o,k] = relu(scale3*extreme + shift3), transposed via LDS.
// max over samples commutes with the monotone BN+ReLU (min if scale<0).
// ---------------------------------------------------------------------------
__global__ __launch_bounds__(256) void feats_kernel(
    const float* __restrict__ y3max, const float* __restrict__ y3min,
    const float* __restrict__ sc3, const float* __restrict__ sh3,
    float* __restrict__ feats)
{
    __shared__ float tile[64][129];
    int blk = blockIdx.x;          // b*16 + kt
    int b = blk >> 4, kt = blk & 15;
    int t = threadIdx.x;
    size_t bk0 = (size_t)(b * KREG + kt * 64);
    #pragma unroll
    for (int i = 0; i < 32; ++i) {
        int idx = i * 256 + t;
        int o = idx & 127, kk = idx >> 7;
        float a = sc3[o];
        float v = (a >= 0.f) ? y3max[(bk0 + kk) * 128 + o]
                             : y3min[(bk0 + kk) * 128 + o];
        tile[kk][o] = fmaxf(fmaf(v, a, sh3[o]), 0.0f);
    }
    __syncthreads();
    #pragma unroll
    for (int i = 0; i < 32; ++i) {
        int idx = i * 256 + t;
        int kk = idx & 63, o = idx >> 6;
        feats[(size_t)b * 128 * KREG + (size_t)o * KREG + kt * 64 + kk] = tile[kk][o];
    }
}

// ---------------------------------------------------------------------------
extern "C" void kernel_launch(void* const* d_in, const int* in_sizes, int n_in,
                              void* d_out, int out_size, void* d_ws, size_t ws_size,
                              hipStream_t stream)
{
    const float* pc  = (const float*)d_in[0];
    const float* w1  = (const float*)d_in[1];
    const float* b1  = (const float*)d_in[2];
    const float* g1  = (const float*)d_in[3];
    const float* be1 = (const float*)d_in[4];
    const float* w2  = (const float*)d_in[5];
    const float* b2  = (const float*)d_in[6];
    const float* g2  = (const float*)d_in[7];
    const float* be2 = (const float*)d_in[8];
    const float* w3  = (const float*)d_in[9];
    const float* b3  = (const float*)d_in[10];
    const float* g3  = (const float*)d_in[11];
    const float* be3 = (const float*)d_in[12];

    float* outC  = (float*)d_out;                      // (16,3,1024)
    float* feats = (float*)d_out + NB * 3 * KREG;      // (16,128,1024)

    const size_t MB = 1024 * 1024;
    char* ws = (char*)d_ws;
    int*   gidx  = (int*)ws;                           // 4 MB
    float* X0    = (float*)(ws + 4 * MB);              // 12 MB (3 x P)
    float* mpart = (float*)(ws + 16 * MB);             // 9216 B
    float* sc1   = (float*)(ws + 16 * MB + 16 * 1024);
    float* sh1   = (float*)(ws + 16 * MB + 17 * 1024);
    float* sc2   = (float*)(ws + 16 * MB + 18 * 1024);
    float* sh2   = (float*)(ws + 16 * MB + 19 * 1024);
    float* sc3   = (float*)(ws + 16 * MB + 20 * 1024);
    float* sh3   = (float*)(ws + 16 * MB + 21 * 1024);
    float* w2t   = (float*)(ws + 16 * MB + 32 * 1024); // 16 KB
    float* w3t   = (float*)(ws + 16 * MB + 64 * 1024); // 32 KB
    float* sum2  = (float*)(ws + 17 * MB);             // 4 MB
    float* sq2   = (float*)(ws + 21 * MB);             // 4 MB
    float* sum3  = (float*)(ws + 25 * MB);             // 8 MB
    float* sq3   = (float*)(ws + 33 * MB);             // 8 MB
    float* y3max = (float*)(ws + 41 * MB);             // 8 MB
    float* y3min = (float*)(ws + 49 * MB);             // 8 MB

    fps_kernel<<<NB, 256, 0, stream>>>(pc, outC);
    ballquery_kernel<<<(NB * KREG) / 4, 256, 0, stream>>>(pc, outC, gidx);
    gather_kernel<<<GATH_BLOCKS, 256, 0, stream>>>(pc, outC, gidx, X0, mpart);
    bn1_finalize<<<1, 64, 0, stream>>>(mpart, w1, b1, g1, be1, sc1, sh1);
    prep_kernel<<<32, 256, 0, stream>>>(w2, w3, w2t, w3t);
    conv12_stats_kernel<<<PTOT / 128, 128, 0, stream>>>(
        X0, w1, b1, sc1, sh1, w2t, b2, sum2, sq2);
    bn_finalize_kernel<<<64, 256, 0, stream>>>(sum2, sq2, g2, be2, sc2, sh2);
    conv123_kernel<<<PTOT / 128, 128, 0, stream>>>(
        X0, w1, b1, sc1, sh1, w2t, b2, sc2, sh2, w3t, b3,
        y3max, y3min, sum3, sq3);
    bn_finalize_kernel<<<128, 256, 0, stream>>>(sum3, sq3, g3, be3, sc3, sh3);
    feats_kernel<<<NB * (KREG / 64), 256, 0, stream>>>(y3max, y3min, sc3, sh3, feats);
}

// Round 5
// 1301.061 us; speedup vs baseline: 1.4703x; 1.0607x over previous
//
#include <hip/hip_runtime.h>
#include <stdint.h>

#define NPTS 4096
#define KREG 1024
#define NS   64
#define NB   16
#define PTOT (NB*KREG*NS)        // 1048576 positions
#define NWAVE (PTOT/64)          // 16384
#define GATH_BLOCKS 256

// ---------------------------------------------------------------------------
// Wave-wide u64 max: 4 DPP mirror levels (VALU) + ds_swizzle xor16 + shfl
// xor32. All 64 lanes end with the max. Exact (integer compare only).
// ---------------------------------------------------------------------------
__device__ __forceinline__ unsigned long long wave_max_u64(unsigned long long k)
{
#define STEP_DPP(ctrl) { \
    unsigned lo = (unsigned)k, hi = (unsigned)(k >> 32); \
    unsigned olo = (unsigned)__builtin_amdgcn_mov_dpp((int)lo, ctrl, 0xF, 0xF, true); \
    unsigned ohi = (unsigned)__builtin_amdgcn_mov_dpp((int)hi, ctrl, 0xF, 0xF, true); \
    unsigned long long o = ((unsigned long long)ohi << 32) | olo; \
    if (o > k) k = o; }
    STEP_DPP(0xB1)    // quad_perm xor1
    STEP_DPP(0x4E)    // quad_perm xor2
    STEP_DPP(0x141)   // row_half_mirror (xor4-equivalent after L1/L2)
    STEP_DPP(0x140)   // row_mirror      (xor8-equivalent)
#undef STEP_DPP
    {   // xor16 via ds_swizzle bit-mode (within each 32-lane half)
        unsigned lo = (unsigned)k, hi = (unsigned)(k >> 32);
        unsigned olo = (unsigned)__builtin_amdgcn_ds_swizzle((int)lo, 0x401F);
        unsigned ohi = (unsigned)__builtin_amdgcn_ds_swizzle((int)hi, 0x401F);
        unsigned long long o = ((unsigned long long)ohi << 32) | olo;
        if (o > k) k = o;
    }
    {   // xor32 via bpermute
        unsigned long long o = __shfl_xor(k, 32, 64);
        if (o > k) k = o;
    }
    return k;
}

// ---------------------------------------------------------------------------
// FPS: one block per batch, 256 threads (4 waves), 16 points/thread in
// REGISTERS. Exact f32 (no FMA) to match numpy. Per-point u64 key
// {dist_bits<<32 | ~p} folded into the distance loop; single-phase wave
// max; cross-wave combine via parity-slot LDS. Centroids are buffered in
// the unused .w words of pcL (LDS only -- no per-iter global store, so no
// vmcnt drain at the barrier) and flushed coalesced at the end.
// ---------------------------------------------------------------------------
__global__ __launch_bounds__(256) void fps_kernel(
    const float* __restrict__ pc, float* __restrict__ outC)
{
    __shared__ float4 pcL[NPTS];                     // 64 KB; .w = centroid buf
    __shared__ alignas(16) unsigned long long wpart[2][4];

    const int b = blockIdx.x;
    const int t = threadIdx.x;
    const int wv = t >> 6;
    const float* px = pc + (size_t)b * 3 * NPTS;

    float lx[16], ly[16], lz[16], md[16];
    #pragma unroll
    for (int j = 0; j < 16; ++j) {
        int p = j * 256 + t;
        float x = px[p], y = px[NPTS + p], z = px[2 * NPTS + p];
        lx[j] = x; ly[j] = y; lz[j] = z;
        pcL[p] = make_float4(x, y, z, 0.0f);
        md[j] = 1e10f;
    }
    __syncthreads();
    float4 cc = pcL[0];
    const unsigned cbase = 0xFFFFFFFFu - (unsigned)t;

    for (int it = 0; it < KREG; ++it) {
        // stash this iteration's centroid into the free .w words (LDS only)
        if (t == 0) {
            pcL[it].w        = cc.x;
            pcL[1024 + it].w = cc.y;
            pcL[2048 + it].w = cc.z;
        }
        unsigned long long best = 0ull;
        #pragma unroll
        for (int j = 0; j < 16; ++j) {
            float dx = __fsub_rn(lx[j], cc.x);
            float dy = __fsub_rn(ly[j], cc.y);
            float dz = __fsub_rn(lz[j], cc.z);
            float d = __fadd_rn(__fadd_rn(__fmul_rn(dx, dx), __fmul_rn(dy, dy)),
                                __fmul_rn(dz, dz));
            float m = fminf(md[j], d);
            md[j] = m;
            unsigned long long cand =
                ((unsigned long long)__float_as_uint(m) << 32) |
                (unsigned long long)(cbase - (unsigned)(j * 256));
            if (cand > best) best = cand;     // u64 max: dist, then first idx
        }
        unsigned long long kmax = wave_max_u64(best);
        if ((t & 63) == 0) wpart[it & 1][wv] = kmax;
        __syncthreads();
        ulonglong2 kab = *(const ulonglong2*)&wpart[it & 1][0];
        ulonglong2 kcd = *(const ulonglong2*)&wpart[it & 1][2];
        unsigned long long ka = (kab.x > kab.y) ? kab.x : kab.y;
        unsigned long long kb = (kcd.x > kcd.y) ? kcd.x : kcd.y;
        unsigned long long kk = (ka > kb) ? ka : kb;
        int f = (int)(0xFFFFFFFFu - (unsigned)kk);
        cc = pcL[f];                          // .w ignored (word-granular LDS)
    }
    __syncthreads();
    // flush centroids: coalesced within each coordinate plane
    for (int i = t; i < KREG; i += 256) {
        outC[(size_t)b * 3 * KREG + i]            = pcL[i].w;
        outC[(size_t)b * 3 * KREG + KREG + i]     = pcL[1024 + i].w;
        outC[(size_t)b * 3 * KREG + 2 * KREG + i] = pcL[2048 + i].w;
    }
}

// ---------------------------------------------------------------------------
// Ball query: one wave per centroid. Exact f32 (c2+x2)-2*dot formula.
// Keeps first NS in-radius indices in ascending order; pads with first index.
// ---------------------------------------------------------------------------
__global__ __launch_bounds__(256) void ballquery_kernel(
    const float* __restrict__ pc, const float* __restrict__ outC,
    int* __restrict__ gidx)
{
    int gw = blockIdx.x * 4 + (threadIdx.x >> 6);
    int lane = threadIdx.x & 63;
    int b = gw >> 10;
    int k = gw & (KREG - 1);
    const float* px = pc + (size_t)b * 3 * NPTS;

    float cx = outC[(size_t)b * 3 * KREG + k];
    float cy = outC[(size_t)b * 3 * KREG + KREG + k];
    float cz = outC[(size_t)b * 3 * KREG + 2 * KREG + k];
    float c2 = __fadd_rn(__fadd_rn(__fmul_rn(cx, cx), __fmul_rn(cy, cy)),
                         __fmul_rn(cz, cz));
    const float r2 = 0.16f;
    int base = gw * NS;
    int cnt = 0;
    int firstidx = -1;

    for (int nb = 0; nb < NPTS / 64; ++nb) {
        int n = nb * 64 + lane;
        float x = px[n], y = px[NPTS + n], z = px[2 * NPTS + n];
        float x2 = __fadd_rn(__fadd_rn(__fmul_rn(x, x), __fmul_rn(y, y)),
                             __fmul_rn(z, z));
        float dt = __fadd_rn(__fadd_rn(__fmul_rn(cx, x), __fmul_rn(cy, y)),
                             __fmul_rn(cz, z));
        float sqd = __fsub_rn(__fadd_rn(c2, x2), __fmul_rn(2.0f, dt));
        bool pred = (sqd <= r2);
        unsigned long long mask = __ballot(pred);
        if (firstidx < 0 && mask) firstidx = nb * 64 + __ffsll((long long)mask) - 1;
        int pos = cnt + __popcll(mask & ((1ull << lane) - 1ull));
        if (pred && pos < NS) gidx[base + pos] = n;
        cnt += __popcll(mask);
        if (cnt >= NS) break;
    }
    if (lane >= cnt) gidx[base + lane] = firstidx;
}

// ---------------------------------------------------------------------------
// Gather grouped coords (planar (3,P)) + 3x3 second-moment partials for BN1.
// ---------------------------------------------------------------------------
__global__ __launch_bounds__(256) void gather_kernel(
    const float* __restrict__ pc, const float* __restrict__ outC,
    const int* __restrict__ gidx, float* __restrict__ X0,
    float* __restrict__ mpart)
{
    float a[9] = {0, 0, 0, 0, 0, 0, 0, 0, 0};
    for (int p = blockIdx.x * 256 + threadIdx.x; p < PTOT; p += GATH_BLOCKS * 256) {
        int bk = p >> 6;
        int b = bk >> 10;
        int k = bk & (KREG - 1);
        int idx = gidx[p];
        const float* px = pc + (size_t)b * 3 * NPTS;
        float x = px[idx]            - outC[(size_t)b * 3 * KREG + k];
        float y = px[NPTS + idx]     - outC[(size_t)b * 3 * KREG + KREG + k];
        float z = px[2 * NPTS + idx] - outC[(size_t)b * 3 * KREG + 2 * KREG + k];
        X0[p] = x; X0[PTOT + p] = y; X0[2 * PTOT + p] = z;
        a[0] += x;     a[1] += y;     a[2] += z;
        a[3] += x * x; a[4] += y * y; a[5] += z * z;
        a[6] += x * y; a[7] += x * z; a[8] += y * z;
    }
    __shared__ float red[4][9];
    int wv = threadIdx.x >> 6;
    #pragma unroll
    for (int q = 0; q < 9; ++q) {
        float v = a[q];
        #pragma unroll
        for (int s = 32; s > 0; s >>= 1) v += __shfl_xor(v, s, 64);
        if ((threadIdx.x & 63) == 0) red[wv][q] = v;
    }
    __syncthreads();
    if (threadIdx.x < 9) {
        mpart[blockIdx.x * 9 + threadIdx.x] =
            red[0][threadIdx.x] + red[1][threadIdx.x] +
            red[2][threadIdx.x] + red[3][threadIdx.x];
    }
}

// ---------------------------------------------------------------------------
// BN1 params analytically from moments: y1 = W1 x + b1 is linear in x.
// ---------------------------------------------------------------------------
__global__ void bn1_finalize(
    const float* __restrict__ mpart, const float* __restrict__ w1,
    const float* __restrict__ b1, const float* __restrict__ g1,
    const float* __restrict__ be1, float* __restrict__ sc1,
    float* __restrict__ sh1)
{
    __shared__ double M[9];
    int t = threadIdx.x;
    if (t < 9) {
        double s = 0;
        for (int i = 0; i < GATH_BLOCKS; ++i) s += (double)mpart[i * 9 + t];
        M[t] = s / (double)PTOT;
    }
    __syncthreads();
    if (t < 64) {
        double mux = M[0], muy = M[1], muz = M[2];
        double xx = M[3], yy = M[4], zz = M[5], xy = M[6], xz = M[7], yz = M[8];
        double wx = w1[t * 3], wy = w1[t * 3 + 1], wz = w1[t * 3 + 2], bb = b1[t];
        double wmu = wx * mux + wy * muy + wz * muz;
        double mean = wmu + bb;
        double ey2 = wx * wx * xx + wy * wy * yy + wz * wz * zz
                   + 2.0 * (wx * wy * xy + wx * wz * xz + wy * wz * yz)
                   + 2.0 * bb * wmu + bb * bb;
        double var = ey2 - mean * mean;
        double scale = (double)g1[t] / sqrt(var + 1e-5);
        sc1[t] = (float)scale;
        sh1[t] = (float)((double)be1[t] - mean * scale);
    }
}

// ---------------------------------------------------------------------------
// Transpose small weight matrices so conv loops read contiguous (-> s_load).
// ---------------------------------------------------------------------------
__global__ __launch_bounds__(256) void prep_kernel(
    const float* __restrict__ w2, const float* __restrict__ w3,
    float* __restrict__ w2t, float* __restrict__ w3t)
{
    int t = blockIdx.x * 256 + threadIdx.x;
    if (t < 4096) w2t[(t & 63) * 64 + (t >> 6)] = w2[t];
    if (t < 8192) w3t[(t & 63) * 128 + (t >> 6)] = w3[t];
}

// ---------------------------------------------------------------------------
// Pass A: conv1+BN1+ReLU -> conv2, accumulate per-channel sum/sumsq of y2.
// 128 threads/block, 1 position/thread. Activations in LDS columns.
// ---------------------------------------------------------------------------
__global__ __launch_bounds__(128) void conv12_stats_kernel(
    const float* __restrict__ X0,
    const float* __restrict__ w1, const float* __restrict__ b1,
    const float* __restrict__ sc1, const float* __restrict__ sh1,
    const float* __restrict__ w2t, const float* __restrict__ b2,
    float* __restrict__ sum2, float* __restrict__ sq2)
{
    __shared__ float xbuf[64 * 128];
    __shared__ float trans[2][8][65];
    const int t = threadIdx.x;
    const int p = blockIdx.x * 128 + t;

    float x = X0[p], y = X0[PTOT + p], z = X0[2 * PTOT + p];
    #pragma unroll
    for (int o = 0; o < 64; ++o) {
        float v = b1[o];
        v = fmaf(w1[o * 3 + 2], z, v);
        v = fmaf(w1[o * 3 + 1], y, v);
        v = fmaf(w1[o * 3 + 0], x, v);
        v = fmaf(v, sc1[o], sh1[o]);
        xbuf[o * 128 + t] = fmaxf(v, 0.0f);
    }
    float acc[64];
    #pragma unroll
    for (int o = 0; o < 64; ++o) acc[o] = b2[o];
    for (int c = 0; c < 64; ++c) {
        float xv = xbuf[c * 128 + t];
        #pragma unroll
        for (int o = 0; o < 64; ++o) acc[o] = fmaf(w2t[c * 64 + o], xv, acc[o]);
    }
    const int wv = t >> 6, lane = t & 63;
    const int gw = blockIdx.x * 2 + wv;
    #pragma unroll
    for (int ch = 0; ch < 8; ++ch) {
        __syncthreads();
        #pragma unroll
        for (int o = 0; o < 8; ++o) trans[wv][o][lane] = acc[ch * 8 + o];
        __syncthreads();
        int row = lane >> 3, seg = lane & 7;
        float s = 0.f, q = 0.f;
        #pragma unroll
        for (int j = 0; j < 8; ++j) {
            float v = trans[wv][row][seg * 8 + j];
            s += v; q = fmaf(v, v, q);
        }
        s += __shfl_xor(s, 1, 64); q += __shfl_xor(q, 1, 64);
        s += __shfl_xor(s, 2, 64); q += __shfl_xor(q, 2, 64);
        s += __shfl_xor(s, 4, 64); q += __shfl_xor(q, 4, 64);
        if (seg == 0) {
            int o = ch * 8 + row;
            sum2[(size_t)o * NWAVE + gw] = s;
            sq2[(size_t)o * NWAVE + gw] = q;
        }
    }
}

// ---------------------------------------------------------------------------
// Generic BN finalize: per-channel block sums wave partials (f64), emits
// scale/shift.
// ---------------------------------------------------------------------------
__global__ __launch_bounds__(256) void bn_finalize_kernel(
    const float* __restrict__ sumb, const float* __restrict__ sqb,
    const float* __restrict__ g, const float* __restrict__ be,
    float* __restrict__ sc, float* __restrict__ sh)
{
    int o = blockIdx.x, t = threadIdx.x;
    double s = 0, q = 0;
    for (int i = t; i < NWAVE; i += 256) {
        s += (double)sumb[(size_t)o * NWAVE + i];
        q += (double)sqb[(size_t)o * NWAVE + i];
    }
    #pragma unroll
    for (int m = 32; m > 0; m >>= 1) {
        s += __shfl_xor(s, m, 64);
        q += __shfl_xor(q, m, 64);
    }
    __shared__ double rs[4], rq[4];
    if ((t & 63) == 0) { rs[t >> 6] = s; rq[t >> 6] = q; }
    __syncthreads();
    if (t == 0) {
        s = rs[0] + rs[1] + rs[2] + rs[3];
        q = rq[0] + rq[1] + rq[2] + rq[3];
        double mean = s / (double)PTOT;
        double var = q / (double)PTOT - mean * mean;
        double scale = (double)g[o] / sqrt(var + 1e-5);
        sc[o] = (float)scale;
        sh[o] = (float)((double)be[o] - mean * scale);
    }
}

// ---------------------------------------------------------------------------
// Pass B: recompute conv1->conv2 (BN params now known), conv3; emit per-(bk,o)
// max/min of y3 plus per-channel sum/sumsq partials. y3 never stored.
// ---------------------------------------------------------------------------
__global__ __launch_bounds__(128) void conv123_kernel(
    const float* __restrict__ X0,
    const float* __restrict__ w1, const float* __restrict__ b1,
    const float* __restrict__ sc1, const float* __restrict__ sh1,
    const float* __restrict__ w2t, const float* __restrict__ b2,
    const float* __restrict__ sc2, const float* __restrict__ sh2,
    const float* __restrict__ w3t, const float* __restrict__ b3,
    float* __restrict__ y3max, float* __restrict__ y3min,
    float* __restrict__ sum3, float* __restrict__ sq3)
{
    __shared__ float xbuf[64 * 128];
    __shared__ float trans[2][8][65];
    const int t = threadIdx.x;
    const int p = blockIdx.x * 128 + t;

    float x = X0[p], y = X0[PTOT + p], z = X0[2 * PTOT + p];
    #pragma unroll
    for (int o = 0; o < 64; ++o) {
        float v = b1[o];
        v = fmaf(w1[o * 3 + 2], z, v);
        v = fmaf(w1[o * 3 + 1], y, v);
        v = fmaf(w1[o * 3 + 0], x, v);
        v = fmaf(v, sc1[o], sh1[o]);
        xbuf[o * 128 + t] = fmaxf(v, 0.0f);
    }
    float acc2[64];
    #pragma unroll
    for (int o = 0; o < 64; ++o) acc2[o] = b2[o];
    for (int c = 0; c < 64; ++c) {
        float xv = xbuf[c * 128 + t];
        #pragma unroll
        for (int o = 0; o < 64; ++o) acc2[o] = fmaf(w2t[c * 64 + o], xv, acc2[o]);
    }
    #pragma unroll
    for (int o = 0; o < 64; ++o) {
        xbuf[o * 128 + t] = fmaxf(fmaf(acc2[o], sc2[o], sh2[o]), 0.0f);
    }
    float acc3[128];
    #pragma unroll
    for (int o = 0; o < 128; ++o) acc3[o] = b3[o];
    for (int c = 0; c < 64; ++c) {
        float xv = xbuf[c * 128 + t];
        #pragma unroll
        for (int o = 0; o < 128; ++o) acc3[o] = fmaf(w3t[c * 128 + o], xv, acc3[o]);
    }
    const int wv = t >> 6, lane = t & 63;
    const int gw = blockIdx.x * 2 + wv;   // == bk (group) index
    #pragma unroll
    for (int ch = 0; ch < 16; ++ch) {
        __syncthreads();
        #pragma unroll
        for (int o = 0; o < 8; ++o) trans[wv][o][lane] = acc3[ch * 8 + o];
        __syncthreads();
        int row = lane >> 3, seg = lane & 7;
        float s = 0.f, q = 0.f, mx = -1e30f, mn = 1e30f;
        #pragma unroll
        for (int j = 0; j < 8; ++j) {
            float v = trans[wv][row][seg * 8 + j];
            s += v; q = fmaf(v, v, q);
            mx = fmaxf(mx, v); mn = fminf(mn, v);
        }
        s += __shfl_xor(s, 1, 64); q += __shfl_xor(q, 1, 64);
        mx = fmaxf(mx, __shfl_xor(mx, 1, 64)); mn = fminf(mn, __shfl_xor(mn, 1, 64));
        s += __shfl_xor(s, 2, 64); q += __shfl_xor(q, 2, 64);
        mx = fmaxf(mx, __shfl_xor(mx, 2, 64)); mn = fminf(mn, __shfl_xor(mn, 2, 64));
        s += __shfl_xor(s, 4, 64); q += __shfl_xor(q, 4, 64);
        mx = fmaxf(mx, __shfl_xor(mx, 4, 64)); mn = fminf(mn, __shfl_xor(mn, 4, 64));
        if (seg == 0) {
            int o = ch * 8 + row;
            y3max[(size_t)gw * 128 + o] = mx;
            y3min[(size_t)gw * 128 + o] = mn;
            sum3[(size_t)o * NWAVE + gw] = s;
            sq3[(size_t)o * NWAVE + gw] = q;
        }
    }
}

// ---------------------------------------------------------------------------
// Final: feats[b,o,k] = relu(scale3*extreme + shift3), transposed via LDS.
// max over samples commutes with the monotone BN+ReLU (min if scale<0).
// ---------------------------------------------------------------------------
__global__ __launch_bounds__(256) void feats_kernel(
    const float* __restrict__ y3max, const float* __restrict__ y3min,
    const float* __restrict__ sc3, const float* __restrict__ sh3,
    float* __restrict__ feats)
{
    __shared__ float tile[64][129];
    int blk = blockIdx.x;          // b*16 + kt
    int b = blk >> 4, kt = blk & 15;
    int t = threadIdx.x;
    size_t bk0 = (size_t)(b * KREG + kt * 64);
    #pragma unroll
    for (int i = 0; i < 32; ++i) {
        int idx = i * 256 + t;
        int o = idx & 127, kk = idx >> 7;
        float a = sc3[o];
        float v = (a >= 0.f) ? y3max[(bk0 + kk) * 128 + o]
                             : y3min[(bk0 + kk) * 128 + o];
        tile[kk][o] = fmaxf(fmaf(v, a, sh3[o]), 0.0f);
    }
    __syncthreads();
    #pragma unroll
    for (int i = 0; i < 32; ++i) {
        int idx = i * 256 + t;
        int kk = idx & 63, o = idx >> 6;
        feats[(size_t)b * 128 * KREG + (size_t)o * KREG + kt * 64 + kk] = tile[kk][o];
    }
}

// ---------------------------------------------------------------------------
extern "C" void kernel_launch(void* const* d_in, const int* in_sizes, int n_in,
                              void* d_out, int out_size, void* d_ws, size_t ws_size,
                              hipStream_t stream)
{
    const float* pc  = (const float*)d_in[0];
    const float* w1  = (const float*)d_in[1];
    const float* b1  = (const float*)d_in[2];
    const float* g1  = (const float*)d_in[3];
    const float* be1 = (const float*)d_in[4];
    const float* w2  = (const float*)d_in[5];
    const float* b2  = (const float*)d_in[6];
    const float* g2  = (const float*)d_in[7];
    const float* be2 = (const float*)d_in[8];
    const float* w3  = (const float*)d_in[9];
    const float* b3  = (const float*)d_in[10];
    const float* g3  = (const float*)d_in[11];
    const float* be3 = (const float*)d_in[12];

    float* outC  = (float*)d_out;                      // (16,3,1024)
    float* feats = (float*)d_out + NB * 3 * KREG;      // (16,128,1024)

    const size_t MB = 1024 * 1024;
    char* ws = (char*)d_ws;
    int*   gidx  = (int*)ws;                           // 4 MB
    float* X0    = (float*)(ws + 4 * MB);              // 12 MB (3 x P)
    float* mpart = (float*)(ws + 16 * MB);             // 9216 B
    float* sc1   = (float*)(ws + 16 * MB + 16 * 1024);
    float* sh1   = (float*)(ws + 16 * MB + 17 * 1024);
    float* sc2   = (float*)(ws + 16 * MB + 18 * 1024);
    float* sh2   = (float*)(ws + 16 * MB + 19 * 1024);
    float* sc3   = (float*)(ws + 16 * MB + 20 * 1024);
    float* sh3   = (float*)(ws + 16 * MB + 21 * 1024);
    float* w2t   = (float*)(ws + 16 * MB + 32 * 1024); // 16 KB
    float* w3t   = (float*)(ws + 16 * MB + 64 * 1024); // 32 KB
    float* sum2  = (float*)(ws + 17 * MB);             // 4 MB
    float* sq2   = (float*)(ws + 21 * MB);             // 4 MB
    float* sum3  = (float*)(ws + 25 * MB);             // 8 MB
    float* sq3   = (float*)(ws + 33 * MB);             // 8 MB
    float* y3max = (float*)(ws + 41 * MB);             // 8 MB
    float* y3min = (float*)(ws + 49 * MB);             // 8 MB

    fps_kernel<<<NB, 256, 0, stream>>>(pc, outC);
    ballquery_kernel<<<(NB * KREG) / 4, 256, 0, stream>>>(pc, outC, gidx);
    gather_kernel<<<GATH_BLOCKS, 256, 0, stream>>>(pc, outC, gidx, X0, mpart);
    bn1_finalize<<<1, 64, 0, stream>>>(mpart, w1, b1, g1, be1, sc1, sh1);
    prep_kernel<<<32, 256, 0, stream>>>(w2, w3, w2t, w3t);
    conv12_stats_kernel<<<PTOT / 128, 128, 0, stream>>>(
        X0, w1, b1, sc1, sh1, w2t, b2, sum2, sq2);
    bn_finalize_kernel<<<64, 256, 0, stream>>>(sum2, sq2, g2, be2, sc2, sh2);
    conv123_kernel<<<PTOT / 128, 128, 0, stream>>>(
        X0, w1, b1, sc1, sh1, w2t, b2, sc2, sh2, w3t, b3,
        y3max, y3min, sum3, sq3);
    bn_finalize_kernel<<<128, 256, 0, stream>>>(sum3, sq3, g3, be3, sc3, sh3);
    feats_kernel<<<NB * (KREG / 64), 256, 0, stream>>>(y3max, y3min, sc3, sh3, feats);
}